// Round 1
// baseline (2090.950 us; speedup 1.0000x reference)
//
#include <hip/hip_runtime.h>
#include <math.h>

#define D64 64
#define KSPLIT 4
#define NBATCH 8

// ---------------- c_sq ----------------
__global__ __launch_bounds__(256) void csq_kernel(const float* __restrict__ cb,
                                                  float* __restrict__ csq, int K) {
  int t = blockIdx.x * blockDim.x + threadIdx.x;
  int row = t >> 6, lane = t & 63;
  if (row >= K) return;
  float v = cb[(size_t)row * D64 + lane];
  v *= v;
  #pragma unroll
  for (int off = 32; off; off >>= 1) v += __shfl_xor(v, off, 64);
  if (lane == 0) csq[row] = v;
}

// ---------------- assignment: top-2 per point over a K-split ----------------
__global__ __launch_bounds__(256) void assign_kernel(
    const float* __restrict__ z, const float* __restrict__ cb,
    const float* __restrict__ csq,
    float* __restrict__ bv1, int* __restrict__ bi1,
    float* __restrict__ bv2, int* __restrict__ bi2,
    int N, int K) {
  int n = blockIdx.x * blockDim.x + threadIdx.x;
  if (n >= N) return;
  int kchunk = K / KSPLIT;
  int k0 = blockIdx.y * kchunk, k1 = k0 + kchunk;

  const float4* z4 = reinterpret_cast<const float4*>(z) + (size_t)n * 16;
  float4 zr[16];
  #pragma unroll
  for (int d = 0; d < 16; ++d) zr[d] = z4[d];

  float b1 = INFINITY, b2 = INFINITY;
  int i1 = -1, i2 = -1;
  const float4* cb4 = reinterpret_cast<const float4*>(cb);

  for (int k = k0; k < k1; k += 2) {
    int ku = __builtin_amdgcn_readfirstlane(k);   // force wave-uniform -> s_load
    const float4* r0 = cb4 + (size_t)ku * 16;
    const float4* r1 = r0 + 16;
    float4 a0 = {0.f, 0.f, 0.f, 0.f}, a1 = {0.f, 0.f, 0.f, 0.f};
    #pragma unroll
    for (int d = 0; d < 16; ++d) {
      float4 c0 = r0[d];
      float4 c1 = r1[d];
      float4 zz = zr[d];
      a0.x = fmaf(c0.x, zz.x, a0.x);
      a0.y = fmaf(c0.y, zz.y, a0.y);
      a0.z = fmaf(c0.z, zz.z, a0.z);
      a0.w = fmaf(c0.w, zz.w, a0.w);
      a1.x = fmaf(c1.x, zz.x, a1.x);
      a1.y = fmaf(c1.y, zz.y, a1.y);
      a1.z = fmaf(c1.z, zz.z, a1.z);
      a1.w = fmaf(c1.w, zz.w, a1.w);
    }
    float s0 = csq[ku]     - 2.0f * ((a0.x + a0.y) + (a0.z + a0.w));
    float s1 = csq[ku + 1] - 2.0f * ((a1.x + a1.y) + (a1.z + a1.w));
    // strict < keeps lowest index on exact ties (matches argmin first-hit)
    if (s0 < b1)      { b2 = b1; i2 = i1; b1 = s0; i1 = ku; }
    else if (s0 < b2) { b2 = s0; i2 = ku; }
    if (s1 < b1)      { b2 = b1; i2 = i1; b1 = s1; i1 = ku + 1; }
    else if (s1 < b2) { b2 = s1; i2 = ku + 1; }
  }
  size_t o = (size_t)blockIdx.y * N + n;
  bv1[o] = b1; bi1[o] = i1; bv2[o] = b2; bi2[o] = i2;
}

// ---------------- merge splits + fp64 rescore + counts + index out ----------------
__global__ __launch_bounds__(256) void merge_kernel(
    const float* __restrict__ z, const float* __restrict__ cb,
    const float* __restrict__ bv1, const int* __restrict__ bi1,
    const float* __restrict__ bv2, const int* __restrict__ bi2,
    const int* __restrict__ batch_raw,
    int* __restrict__ fidx, float* __restrict__ out_idx,
    unsigned int* __restrict__ counts,
    int N, int K) {
  int n = blockIdx.x * blockDim.x + threadIdx.x;
  if (n >= N) return;

  float b1 = INFINITY, b2 = INFINITY; int i1 = -1, i2 = -1;
  #pragma unroll
  for (int s = 0; s < KSPLIT; ++s) {
    size_t o = (size_t)s * N + n;
    float v = bv1[o]; int j = bi1[o];
    if (v < b1)      { b2 = b1; i2 = i1; b1 = v; i1 = j; }
    else if (v < b2) { b2 = v; i2 = j; }
    v = bv2[o]; j = bi2[o];
    if (v < b1)      { b2 = b1; i2 = i1; b1 = v; i1 = j; }
    else if (v < b2) { b2 = v; i2 = j; }
  }

  int final_i = i1;
  if (b2 - b1 < 1e-3f && i2 >= 0) {
    // exact fp64 rescore of the two candidates
    const float* zp  = z  + (size_t)n  * D64;
    const float* c1p = cb + (size_t)i1 * D64;
    const float* c2p = cb + (size_t)i2 * D64;
    double d0 = 0.0, d1 = 0.0;
    for (int d = 0; d < D64; ++d) {
      double t0 = (double)zp[d] - (double)c1p[d];
      double t1 = (double)zp[d] - (double)c2p[d];
      d0 += t0 * t0;
      d1 += t1 * t1;
    }
    if (d1 < d0 || (d1 == d0 && i2 < i1)) final_i = i2;
  }

  fidx[n] = final_i;
  out_idx[n] = (float)final_i;

  // batch_ids dtype auto-detect: ids are sorted in [0,8); if the buffer is
  // int64, int32-slot [N-1] is the high word of element N/2-1 == 0; if int32,
  // it's the last id (==7 w.o.p.).
  int is64 = (batch_raw[N - 1] == 0) ? 1 : 0;
  int b = is64 ? batch_raw[2 * n] : batch_raw[n];
  atomicAdd(&counts[(size_t)b * K + final_i], 1u);
}

// ---------------- gather + straight-through + SSE ----------------
__global__ __launch_bounds__(256) void quant_kernel(
    const float* __restrict__ z, const float* __restrict__ cb,
    const int* __restrict__ fidx, float* __restrict__ outq,
    double* __restrict__ sse, int N) {
  __shared__ double red[4];
  int g = blockIdx.x * blockDim.x + threadIdx.x;   // float4 index
  int total4 = N * 16;
  double local = 0.0;
  if (g < total4) {
    int n = g >> 4, d4 = g & 15;
    int k = fidx[n];
    float4 zz = reinterpret_cast<const float4*>(z)[g];
    float4 qq = reinterpret_cast<const float4*>(cb)[(size_t)k * 16 + d4];
    float4 t  = {qq.x - zz.x, qq.y - zz.y, qq.z - zz.z, qq.w - zz.w};
    float4 st = {zz.x + t.x, zz.y + t.y, zz.z + t.z, zz.w + t.w};
    reinterpret_cast<float4*>(outq)[g] = st;
    local = (double)t.x * t.x + (double)t.y * t.y +
            (double)t.z * t.z + (double)t.w * t.w;
  }
  #pragma unroll
  for (int off = 32; off; off >>= 1) local += __shfl_xor(local, off, 64);
  int lane = threadIdx.x & 63, w = threadIdx.x >> 6;
  if (lane == 0) red[w] = local;
  __syncthreads();
  if (threadIdx.x == 0) {
    atomicAdd(sse, red[0] + red[1] + red[2] + red[3]);
  }
}

// ---------------- per-batch entropy / perplexity / unique ----------------
__global__ __launch_bounds__(256) void stats_kernel(
    const unsigned int* __restrict__ counts,
    double* __restrict__ perp, double* __restrict__ ent,
    double* __restrict__ uniq, int K) {
  __shared__ double sh4[4], she[4], shu[4];
  int b = blockIdx.x;
  const unsigned int* c = counts + (size_t)b * K;
  int lane = threadIdx.x & 63, w = threadIdx.x >> 6;

  double tot = 0.0;
  for (int k = threadIdx.x; k < K; k += blockDim.x) tot += (double)c[k];
  #pragma unroll
  for (int off = 32; off; off >>= 1) tot += __shfl_xor(tot, off, 64);
  if (lane == 0) sh4[w] = tot;
  __syncthreads();
  double total = sh4[0] + sh4[1] + sh4[2] + sh4[3];
  double denom = fmax(total, 1.0);

  double e = 0.0, u = 0.0;
  for (int k = threadIdx.x; k < K; k += blockDim.x) {
    double cc = (double)c[k];
    double p = cc / denom;
    e -= p * log(p + 1e-10);
    if (cc > 0.0) u += 1.0;
  }
  #pragma unroll
  for (int off = 32; off; off >>= 1) {
    e += __shfl_xor(e, off, 64);
    u += __shfl_xor(u, off, 64);
  }
  if (lane == 0) { she[w] = e; shu[w] = u; }
  __syncthreads();
  if (threadIdx.x == 0) {
    double E = she[0] + she[1] + she[2] + she[3];
    double U = shu[0] + shu[1] + shu[2] + shu[3];
    ent[b] = E; perp[b] = exp(E); uniq[b] = U;
  }
}

// ---------------- finalize scalars ----------------
__global__ void final_kernel(const double* __restrict__ sse,
                             const double* __restrict__ perp,
                             const double* __restrict__ ent,
                             const double* __restrict__ uniq,
                             float* __restrict__ out, int N) {
  if (threadIdx.x == 0 && blockIdx.x == 0) {
    double mp = 0.0, me = 0.0, mu = 0.0;
    for (int b = 0; b < NBATCH; ++b) { mp += perp[b]; me += ent[b]; mu += uniq[b]; }
    mp /= NBATCH; me /= NBATCH; mu /= NBATCH;
    double loss = *sse / ((double)N * (double)D64);
    size_t voff = (size_t)N * D64;       // vq_loss
    size_t coff = voff + 1;              // commitment_loss (identical value)
    size_t poff = coff + 1 + (size_t)N;  // avg_perplexity
    out[voff] = (float)loss;
    out[coff] = (float)loss;
    out[poff]     = (float)mp;
    out[poff + 1] = (float)me;
    out[poff + 2] = (float)mu;
  }
}

extern "C" void kernel_launch(void* const* d_in, const int* in_sizes, int n_in,
                              void* d_out, int out_size, void* d_ws, size_t ws_size,
                              hipStream_t stream) {
  const float* z   = (const float*)d_in[0];
  const int*   bid = (const int*)d_in[1];
  const float* cb  = (const float*)d_in[2];
  int N = in_sizes[1];            // 65536
  int Dd = in_sizes[0] / N;       // 64
  int K = in_sizes[2] / Dd;       // 8192
  float* out = (float*)d_out;

  // workspace layout
  char* ws = (char*)d_ws;
  size_t off = 0;
  unsigned int* counts = (unsigned int*)(ws + off); off += (size_t)NBATCH * K * 4;
  double* sse  = (double*)(ws + off); off += 8;
  double* perp = (double*)(ws + off); off += 8 * NBATCH;
  double* ent  = (double*)(ws + off); off += 8 * NBATCH;
  double* uniq = (double*)(ws + off); off += 8 * NBATCH;
  float*  csq  = (float*)(ws + off);  off += (size_t)K * 4;
  float*  bv1  = (float*)(ws + off);  off += (size_t)KSPLIT * N * 4;
  int*    bi1  = (int*)(ws + off);    off += (size_t)KSPLIT * N * 4;
  float*  bv2  = (float*)(ws + off);  off += (size_t)KSPLIT * N * 4;
  int*    bi2  = (int*)(ws + off);    off += (size_t)KSPLIT * N * 4;
  int*    fidx = (int*)(ws + off);    off += (size_t)N * 4;

  // zero counts + sse (ws is poisoned, not re-poisoned between replays)
  hipMemsetAsync(d_ws, 0, (size_t)NBATCH * K * 4 + 8, stream);

  size_t ioff = (size_t)N * Dd + 2;   // encoding_indices offset in out

  csq_kernel<<<(K * 64 + 255) / 256, 256, 0, stream>>>(cb, csq, K);

  dim3 ag((N + 255) / 256, KSPLIT);
  assign_kernel<<<ag, 256, 0, stream>>>(z, cb, csq, bv1, bi1, bv2, bi2, N, K);

  merge_kernel<<<(N + 255) / 256, 256, 0, stream>>>(
      z, cb, bv1, bi1, bv2, bi2, bid, fidx, out + ioff, counts, N, K);

  quant_kernel<<<(N * 16 + 255) / 256, 256, 0, stream>>>(z, cb, fidx, out, sse, N);

  stats_kernel<<<NBATCH, 256, 0, stream>>>(counts, perp, ent, uniq, K);

  final_kernel<<<1, 64, 0, stream>>>(sse, perp, ent, uniq, out, N);
}

// Round 3
// 1109.616 us; speedup vs baseline: 1.8844x; 1.8844x over previous
//
#include <hip/hip_runtime.h>
#include <math.h>

#define D64 64
#define NBATCH 8
#define KB_SIZE 512          // codes per filter block
#define NKB 16               // K / KB_SIZE
#define BAND 3.0f

typedef short s16x8 __attribute__((ext_vector_type(8)));   // 8 bf16 (bit pattern)
typedef float f32x4 __attribute__((ext_vector_type(4)));

__device__ inline short f2bf(float f) {
  unsigned u = __builtin_bit_cast(unsigned, f);
  unsigned r = (u + 0x7FFFu + ((u >> 16) & 1u)) >> 16;
  return (short)r;
}

__device__ inline unsigned long long packsc(float s, int idx) {
  unsigned u = __builtin_bit_cast(unsigned, s);
  u = (u & 0x80000000u) ? ~u : (u | 0x80000000u);   // order-preserving
  return ((unsigned long long)u << 32) | (unsigned)idx;
}
__device__ inline float unpack_s(unsigned long long p) {
  unsigned u = (unsigned)(p >> 32);
  u = (u >> 31) ? (u ^ 0x80000000u) : ~u;
  return __builtin_bit_cast(float, u);
}

// ---------------- c_sq + bf16 convert ----------------
__global__ __launch_bounds__(256) void csq_cvt_kernel(
    const float* __restrict__ cb, float* __restrict__ csq,
    short* __restrict__ cbh, int K) {
  int t = blockIdx.x * blockDim.x + threadIdx.x;
  int row = t >> 6, lane = t & 63;
  if (row >= K) return;
  float v = cb[(size_t)row * D64 + lane];
  cbh[(size_t)row * D64 + lane] = f2bf(v);
  v *= v;
  #pragma unroll
  for (int off = 32; off; off >>= 1) v += __shfl_xor(v, off, 64);
  if (lane == 0) csq[row] = v;
}

// ---------------- MFMA bf16 filter: per-point block-mins ----------------
// wave = 32 points (2 row-tiles of 16), block = 4 waves = 128 points.
__global__ __launch_bounds__(256) void filter_kernel(
    const float* __restrict__ z, const short* __restrict__ cbh,
    const float* __restrict__ csq, float* __restrict__ bm, int N, int K) {
  int wave = threadIdx.x >> 6;
  int l = threadIdx.x & 63;
  int lr = l & 15, lg = l >> 4;
  int base = blockIdx.x * 128 + wave * 32;

  // A fragments: A[rt][kh], lane holds z[row][kh*32 + lg*8 + j], j=0..7
  s16x8 A[2][2];
  #pragma unroll
  for (int rt = 0; rt < 2; ++rt) {
    int row = base + rt * 16 + lr;
    #pragma unroll
    for (int kh = 0; kh < 2; ++kh) {
      const float4* zp = reinterpret_cast<const float4*>(
          z + (size_t)row * D64 + kh * 32 + lg * 8);
      float4 p0 = zp[0], p1 = zp[1];
      s16x8 t;
      t[0] = f2bf(p0.x); t[1] = f2bf(p0.y); t[2] = f2bf(p0.z); t[3] = f2bf(p0.w);
      t[4] = f2bf(p1.x); t[5] = f2bf(p1.y); t[6] = f2bf(p1.z); t[7] = f2bf(p1.w);
      A[rt][kh] = t;
    }
  }

  float rmin[2][4];
  #pragma unroll
  for (int rt = 0; rt < 2; ++rt)
    #pragma unroll
    for (int r = 0; r < 4; ++r) rmin[rt][r] = INFINITY;

  // B pointer: code = t2*16 + lr, element block lg (d = lg*8), +4 for d>=32
  const s16x8* bp = reinterpret_cast<const s16x8*>(cbh) + (size_t)lr * 8 + lg;
  const float* cqp = csq + lr;

  for (int kb = 0; kb < NKB; ++kb) {
    #pragma unroll 4
    for (int t2 = 0; t2 < 32; ++t2) {
      s16x8 B0 = bp[0];
      s16x8 B1 = bp[4];
      float cq = *cqp;
      bp += 128;       // 16 codes * 8 frags
      cqp += 16;
      #pragma unroll
      for (int rt = 0; rt < 2; ++rt) {
        f32x4 acc = {0.f, 0.f, 0.f, 0.f};
        acc = __builtin_amdgcn_mfma_f32_16x16x32_bf16(A[rt][0], B0, acc, 0, 0, 0);
        acc = __builtin_amdgcn_mfma_f32_16x16x32_bf16(A[rt][1], B1, acc, 0, 0, 0);
        #pragma unroll
        for (int r = 0; r < 4; ++r) {
          float s = fmaf(-2.0f, acc[r], cq);
          rmin[rt][r] = fminf(rmin[rt][r], s);
        }
      }
    }
    // reduce over the 16 cols (lane bits 0..3), store block-min
    #pragma unroll
    for (int rt = 0; rt < 2; ++rt)
      #pragma unroll
      for (int r = 0; r < 4; ++r) {
        float v = rmin[rt][r];
        v = fminf(v, __shfl_xor(v, 1, 64));
        v = fminf(v, __shfl_xor(v, 2, 64));
        v = fminf(v, __shfl_xor(v, 4, 64));
        v = fminf(v, __shfl_xor(v, 8, 64));
        if (lr == 0)
          bm[(size_t)kb * N + base + rt * 16 + lg * 4 + r] = v;
        rmin[rt][r] = INFINITY;
      }
  }
}

// ---------------- select qualifying blocks per point ----------------
__global__ __launch_bounds__(256) void select_kernel(
    const float* __restrict__ bm, int* __restrict__ lens,
    int* __restrict__ lists, int N) {
  int n = blockIdx.x * blockDim.x + threadIdx.x;
  if (n >= N) return;
  int lane = threadIdx.x & 63;
  float v[NKB];
  float m = INFINITY;
  #pragma unroll
  for (int kb = 0; kb < NKB; ++kb) {
    v[kb] = bm[(size_t)kb * N + n];
    m = fminf(m, v[kb]);
  }
  float thr = m + BAND;
  #pragma unroll
  for (int kb = 0; kb < NKB; ++kb) {
    bool q = v[kb] <= thr;
    unsigned long long mask = __ballot(q);
    int cnt = __popcll(mask);
    int basepos = 0;
    if (cnt) {
      if (lane == 0) basepos = atomicAdd(&lens[kb], cnt);
      basepos = __shfl(basepos, 0, 64);
      if (q) {
        int off = __popcll(mask & ((1ull << lane) - 1ull));
        lists[(size_t)kb * N + basepos + off] = n;
      }
    }
  }
}

// ---------------- exact fp32 rescan of a 512-code block ----------------
__global__ __launch_bounds__(256) void scan_kernel(
    const float* __restrict__ z, const float* __restrict__ cb,
    const float* __restrict__ csq,
    const int* __restrict__ lens, const int* __restrict__ lists,
    unsigned long long* __restrict__ a1, unsigned long long* __restrict__ a2,
    int N, int K) {
  int kb = blockIdx.x >> 8;
  int chunk = blockIdx.x & 255;
  int len = lens[kb];
  if (chunk * 256 >= len) return;           // uniform across block

  __shared__ float lcb[2][64 * D64];
  __shared__ float lcsq[KB_SIZE];

  int i = chunk * 256 + (int)threadIdx.x;
  bool active = i < len;
  int n = lists[(size_t)kb * N + (active ? i : chunk * 256)];
  int k0 = kb * KB_SIZE;

  // stage csq chunk
  for (int q = threadIdx.x; q < KB_SIZE; q += 256) lcsq[q] = csq[k0 + q];

  // z row into registers
  const float4* z4 = reinterpret_cast<const float4*>(z) + (size_t)n * 16;
  float4 zr[16];
  #pragma unroll
  for (int d = 0; d < 16; ++d) zr[d] = z4[d];

  // stage tile 0
  {
    const float4* src = reinterpret_cast<const float4*>(cb + (size_t)k0 * D64);
    float4* dst = reinterpret_cast<float4*>(lcb[0]);
    #pragma unroll
    for (int q = 0; q < 4; ++q) dst[threadIdx.x + q * 256] = src[threadIdx.x + q * 256];
  }
  __syncthreads();

  float b1 = INFINITY, b2 = INFINITY;
  int i1 = -1, i2 = -1;

  for (int t = 0; t < 8; ++t) {
    if (t < 7) {
      const float4* src = reinterpret_cast<const float4*>(
          cb + (size_t)(k0 + (t + 1) * 64) * D64);
      float4* dst = reinterpret_cast<float4*>(lcb[(t + 1) & 1]);
      #pragma unroll
      for (int q = 0; q < 4; ++q) dst[threadIdx.x + q * 256] = src[threadIdx.x + q * 256];
    }
    const float* buf = lcb[t & 1];
    for (int c = 0; c < 64; c += 2) {
      const float4* c0 = reinterpret_cast<const float4*>(buf + c * D64);
      const float4* c1 = c0 + 16;
      float4 a0 = {0.f, 0.f, 0.f, 0.f}, a1v = {0.f, 0.f, 0.f, 0.f};
      #pragma unroll
      for (int d = 0; d < 16; ++d) {
        float4 q0 = c0[d], q1 = c1[d], zz = zr[d];
        a0.x = fmaf(q0.x, zz.x, a0.x);
        a0.y = fmaf(q0.y, zz.y, a0.y);
        a0.z = fmaf(q0.z, zz.z, a0.z);
        a0.w = fmaf(q0.w, zz.w, a0.w);
        a1v.x = fmaf(q1.x, zz.x, a1v.x);
        a1v.y = fmaf(q1.y, zz.y, a1v.y);
        a1v.z = fmaf(q1.z, zz.z, a1v.z);
        a1v.w = fmaf(q1.w, zz.w, a1v.w);
      }
      int kg = k0 + t * 64 + c;
      float s0 = lcsq[t * 64 + c]     - 2.0f * ((a0.x + a0.y) + (a0.z + a0.w));
      float s1 = lcsq[t * 64 + c + 1] - 2.0f * ((a1v.x + a1v.y) + (a1v.z + a1v.w));
      // branchless top-2, strict < keeps lowest index on ties
      bool lt1 = s0 < b1;
      float cand = lt1 ? b1 : s0; int ci = lt1 ? i1 : kg;
      b1 = lt1 ? s0 : b1;  i1 = lt1 ? kg : i1;
      bool lt2 = cand < b2;
      b2 = lt2 ? cand : b2; i2 = lt2 ? ci : i2;
      lt1 = s1 < b1;
      cand = lt1 ? b1 : s1; ci = lt1 ? i1 : (kg + 1);
      b1 = lt1 ? s1 : b1;  i1 = lt1 ? (kg + 1) : i1;
      lt2 = cand < b2;
      b2 = lt2 ? cand : b2; i2 = lt2 ? ci : i2;
    }
    __syncthreads();
  }

  if (active) {
    unsigned long long pk = packsc(b1, i1);
    unsigned long long old1 = atomicMin(&a1[n], pk);
    unsigned long long loser = old1 > pk ? old1 : pk;
    atomicMin(&a2[n], loser);
    atomicMin(&a2[n], packsc(b2, i2));
  }
}

// ---------------- merge + fp64 tiebreak + counts + index out ----------------
__global__ __launch_bounds__(256) void final_assign_kernel(
    const float* __restrict__ z, const float* __restrict__ cb,
    const unsigned long long* __restrict__ a1,
    const unsigned long long* __restrict__ a2,
    const int* __restrict__ batch_raw,
    int* __restrict__ fidx, float* __restrict__ out_idx,
    unsigned int* __restrict__ counts, int N, int K) {
  int n = blockIdx.x * blockDim.x + threadIdx.x;
  if (n >= N) return;
  unsigned long long p1 = a1[n], p2 = a2[n];
  float b1 = unpack_s(p1), b2 = unpack_s(p2);
  int i1 = (int)(p1 & 0xFFFFFFFFull);
  int i2 = (int)(p2 & 0xFFFFFFFFull);

  int final_i = i1;
  if (p2 != 0xFFFFFFFFFFFFFFFFull && (b2 - b1) < 1e-3f) {
    const float* zp  = z  + (size_t)n  * D64;
    const float* c1p = cb + (size_t)i1 * D64;
    const float* c2p = cb + (size_t)i2 * D64;
    double d0 = 0.0, d1 = 0.0;
    for (int d = 0; d < D64; ++d) {
      double t0 = (double)zp[d] - (double)c1p[d];
      double t1 = (double)zp[d] - (double)c2p[d];
      d0 += t0 * t0;
      d1 += t1 * t1;
    }
    if (d1 < d0 || (d1 == d0 && i2 < i1)) final_i = i2;
  }

  fidx[n] = final_i;
  out_idx[n] = (float)final_i;

  int is64 = (batch_raw[N - 1] == 0) ? 1 : 0;
  int b = is64 ? batch_raw[2 * n] : batch_raw[n];
  atomicAdd(&counts[(size_t)b * K + final_i], 1u);
}

// ---------------- gather + straight-through + SSE ----------------
__global__ __launch_bounds__(256) void quant_kernel(
    const float* __restrict__ z, const float* __restrict__ cb,
    const int* __restrict__ fidx, float* __restrict__ outq,
    double* __restrict__ sse, int N) {
  __shared__ double red[4];
  int g = blockIdx.x * blockDim.x + threadIdx.x;
  int total4 = N * 16;
  double local = 0.0;
  if (g < total4) {
    int n = g >> 4, d4 = g & 15;
    int k = fidx[n];
    float4 zz = reinterpret_cast<const float4*>(z)[g];
    float4 qq = reinterpret_cast<const float4*>(cb)[(size_t)k * 16 + d4];
    float4 t = {qq.x - zz.x, qq.y - zz.y, qq.z - zz.z, qq.w - zz.w};
    float4 st = {zz.x + t.x, zz.y + t.y, zz.z + t.z, zz.w + t.w};
    reinterpret_cast<float4*>(outq)[g] = st;
    local = (double)t.x * t.x + (double)t.y * t.y +
            (double)t.z * t.z + (double)t.w * t.w;
  }
  #pragma unroll
  for (int off = 32; off; off >>= 1) local += __shfl_xor(local, off, 64);
  int lane = threadIdx.x & 63, w = threadIdx.x >> 6;
  if (lane == 0) red[w] = local;
  __syncthreads();
  if (threadIdx.x == 0) atomicAdd(sse, red[0] + red[1] + red[2] + red[3]);
}

// ---------------- per-batch entropy / perplexity / unique ----------------
__global__ __launch_bounds__(256) void stats_kernel(
    const unsigned int* __restrict__ counts,
    double* __restrict__ perp, double* __restrict__ ent,
    double* __restrict__ uniq, int K) {
  __shared__ double sh4[4], she[4], shu[4];
  int b = blockIdx.x;
  const unsigned int* c = counts + (size_t)b * K;
  int lane = threadIdx.x & 63, w = threadIdx.x >> 6;

  double tot = 0.0;
  for (int k = threadIdx.x; k < K; k += blockDim.x) tot += (double)c[k];
  #pragma unroll
  for (int off = 32; off; off >>= 1) tot += __shfl_xor(tot, off, 64);
  if (lane == 0) sh4[w] = tot;
  __syncthreads();
  double total = sh4[0] + sh4[1] + sh4[2] + sh4[3];
  double denom = fmax(total, 1.0);

  double e = 0.0, u = 0.0;
  for (int k = threadIdx.x; k < K; k += blockDim.x) {
    double cc = (double)c[k];
    double p = cc / denom;
    e -= p * log(p + 1e-10);
    if (cc > 0.0) u += 1.0;
  }
  #pragma unroll
  for (int off = 32; off; off >>= 1) {
    e += __shfl_xor(e, off, 64);
    u += __shfl_xor(u, off, 64);
  }
  if (lane == 0) { she[w] = e; shu[w] = u; }
  __syncthreads();
  if (threadIdx.x == 0) {
    double E = she[0] + she[1] + she[2] + she[3];
    double U = shu[0] + shu[1] + shu[2] + shu[3];
    ent[b] = E; perp[b] = exp(E); uniq[b] = U;
  }
}

// ---------------- finalize scalars ----------------
__global__ void final_kernel(const double* __restrict__ sse,
                             const double* __restrict__ perp,
                             const double* __restrict__ ent,
                             const double* __restrict__ uniq,
                             float* __restrict__ out, int N) {
  if (threadIdx.x == 0 && blockIdx.x == 0) {
    double mp = 0.0, me = 0.0, mu = 0.0;
    for (int b = 0; b < NBATCH; ++b) { mp += perp[b]; me += ent[b]; mu += uniq[b]; }
    mp /= NBATCH; me /= NBATCH; mu /= NBATCH;
    double loss = *sse / ((double)N * (double)D64);
    size_t voff = (size_t)N * D64;
    size_t coff = voff + 1;
    size_t poff = coff + 1 + (size_t)N;
    out[voff] = (float)loss;
    out[coff] = (float)loss;
    out[poff] = (float)mp;
    out[poff + 1] = (float)me;
    out[poff + 2] = (float)mu;
  }
}

extern "C" void kernel_launch(void* const* d_in, const int* in_sizes, int n_in,
                              void* d_out, int out_size, void* d_ws, size_t ws_size,
                              hipStream_t stream) {
  const float* z = (const float*)d_in[0];
  const int* bid = (const int*)d_in[1];
  const float* cb = (const float*)d_in[2];
  int N = in_sizes[1];
  int Dd = in_sizes[0] / N;
  int K = in_sizes[2] / Dd;
  float* out = (float*)d_out;

  // workspace layout (256B-aligned chunks)
  char* ws = (char*)d_ws;
  size_t off = 0;
  auto alloc = [&](size_t bytes) {
    void* p = ws + off;
    off += (bytes + 255) & ~(size_t)255;
    return p;
  };
  unsigned int* counts = (unsigned int*)alloc((size_t)NBATCH * K * 4);
  double* sse  = (double*)alloc(8);
  double* perp = (double*)alloc(8 * NBATCH);
  double* ent  = (double*)alloc(8 * NBATCH);
  double* uniq = (double*)alloc(8 * NBATCH);
  float* csq = (float*)alloc((size_t)K * 4);
  short* cbh = (short*)alloc((size_t)K * D64 * 2);
  float* bm = (float*)alloc((size_t)NKB * N * 4);
  int* lens = (int*)alloc(NKB * 4);
  int* lists = (int*)alloc((size_t)NKB * N * 4);
  unsigned long long* a1 = (unsigned long long*)alloc((size_t)N * 8);
  unsigned long long* a2 = (unsigned long long*)alloc((size_t)N * 8);
  int* fidx = (int*)alloc((size_t)N * 4);

  (void)hipMemsetAsync(counts, 0, (size_t)NBATCH * K * 4, stream);
  (void)hipMemsetAsync(sse, 0, 8, stream);
  (void)hipMemsetAsync(lens, 0, NKB * 4, stream);
  (void)hipMemsetAsync(a1, 0xFF, (size_t)N * 8, stream);
  (void)hipMemsetAsync(a2, 0xFF, (size_t)N * 8, stream);

  size_t ioff = (size_t)N * Dd + 2;

  csq_cvt_kernel<<<(K * 64 + 255) / 256, 256, 0, stream>>>(cb, csq, cbh, K);
  filter_kernel<<<N / 128, 256, 0, stream>>>(z, cbh, csq, bm, N, K);
  select_kernel<<<(N + 255) / 256, 256, 0, stream>>>(bm, lens, lists, N);
  scan_kernel<<<NKB * 256, 256, 0, stream>>>(z, cb, csq, lens, lists, a1, a2, N, K);
  final_assign_kernel<<<(N + 255) / 256, 256, 0, stream>>>(
      z, cb, a1, a2, bid, fidx, out + ioff, counts, N, K);
  quant_kernel<<<(N * 16 + 255) / 256, 256, 0, stream>>>(z, cb, fidx, out, sse, N);
  stats_kernel<<<NBATCH, 256, 0, stream>>>(counts, perp, ent, uniq, K);
  final_kernel<<<1, 64, 0, stream>>>(sse, perp, ent, uniq, out, N);
}

// Round 4
// 679.961 us; speedup vs baseline: 3.0751x; 1.6319x over previous
//
#include <hip/hip_runtime.h>
#include <math.h>

#define D64 64
#define NBATCH 8
#define CBAND 2.0f
#define NSLOT 16

typedef short s16x8 __attribute__((ext_vector_type(8)));   // 8 bf16 (bit pattern)
typedef float f32x4 __attribute__((ext_vector_type(4)));

__device__ inline short f2bf(float f) {
  unsigned u = __builtin_bit_cast(unsigned, f);
  unsigned r = (u + 0x7FFFu + ((u >> 16) & 1u)) >> 16;
  return (short)r;
}

// ---------------- c_sq + bf16 convert ----------------
__global__ __launch_bounds__(256) void csq_cvt_kernel(
    const float* __restrict__ cb, float* __restrict__ csq,
    short* __restrict__ cbh, int K) {
  int t = blockIdx.x * blockDim.x + threadIdx.x;
  int row = t >> 6, lane = t & 63;
  if (row >= K) return;
  float v = cb[(size_t)row * D64 + lane];
  cbh[(size_t)row * D64 + lane] = f2bf(v);
  v *= v;
  #pragma unroll
  for (int off = 32; off; off >>= 1) v += __shfl_xor(v, off, 64);
  if (lane == 0) csq[row] = v;
}

// ---------------- MFMA pass A: per-point global bf16-score min ----------------
// wave = 32 points (2 row-tiles of 16), block = 4 waves = 128 points.
__global__ __launch_bounds__(256) void filter_min_kernel(
    const float* __restrict__ z, const short* __restrict__ cbh,
    const float* __restrict__ csq, float* __restrict__ pmin, int N, int K) {
  int wave = threadIdx.x >> 6;
  int l = threadIdx.x & 63;
  int lr = l & 15, lg = l >> 4;
  int base = blockIdx.x * 128 + wave * 32;

  s16x8 A[2][2];
  #pragma unroll
  for (int rt = 0; rt < 2; ++rt) {
    int row = base + rt * 16 + lr;
    #pragma unroll
    for (int kh = 0; kh < 2; ++kh) {
      const float4* zp = reinterpret_cast<const float4*>(
          z + (size_t)row * D64 + kh * 32 + lg * 8);
      float4 p0 = zp[0], p1 = zp[1];
      s16x8 t;
      t[0] = f2bf(p0.x); t[1] = f2bf(p0.y); t[2] = f2bf(p0.z); t[3] = f2bf(p0.w);
      t[4] = f2bf(p1.x); t[5] = f2bf(p1.y); t[6] = f2bf(p1.z); t[7] = f2bf(p1.w);
      A[rt][kh] = t;
    }
  }

  float rmin[2][4];
  #pragma unroll
  for (int rt = 0; rt < 2; ++rt)
    #pragma unroll
    for (int r = 0; r < 4; ++r) rmin[rt][r] = INFINITY;

  const s16x8* bp = reinterpret_cast<const s16x8*>(cbh) + (size_t)lr * 8 + lg;
  const float* cqp = csq + lr;
  int niter = K / 16;

  #pragma unroll 4
  for (int t2 = 0; t2 < niter; ++t2) {
    s16x8 B0 = bp[0];
    s16x8 B1 = bp[4];
    float cq = *cqp;
    bp += 128;       // 16 codes * 8 frags
    cqp += 16;
    #pragma unroll
    for (int rt = 0; rt < 2; ++rt) {
      f32x4 acc = {0.f, 0.f, 0.f, 0.f};
      acc = __builtin_amdgcn_mfma_f32_16x16x32_bf16(A[rt][0], B0, acc, 0, 0, 0);
      acc = __builtin_amdgcn_mfma_f32_16x16x32_bf16(A[rt][1], B1, acc, 0, 0, 0);
      #pragma unroll
      for (int r = 0; r < 4; ++r) {
        float s = fmaf(-2.0f, acc[r], cq);
        rmin[rt][r] = fminf(rmin[rt][r], s);
      }
    }
  }

  // reduce over the 16 cols (lane bits 0..3), store per-point min
  #pragma unroll
  for (int rt = 0; rt < 2; ++rt)
    #pragma unroll
    for (int r = 0; r < 4; ++r) {
      float v = rmin[rt][r];
      v = fminf(v, __shfl_xor(v, 1, 64));
      v = fminf(v, __shfl_xor(v, 2, 64));
      v = fminf(v, __shfl_xor(v, 4, 64));
      v = fminf(v, __shfl_xor(v, 8, 64));
      if (lr == 0)
        pmin[base + rt * 16 + lg * 4 + r] = v;
    }
}

// ---------------- MFMA pass B: emit candidate codes within band ----------------
__global__ __launch_bounds__(256) void emit_kernel(
    const float* __restrict__ z, const short* __restrict__ cbh,
    const float* __restrict__ csq, const float* __restrict__ pmin,
    unsigned int* __restrict__ pcnt, int* __restrict__ cand, int N, int K) {
  int wave = threadIdx.x >> 6;
  int l = threadIdx.x & 63;
  int lr = l & 15, lg = l >> 4;
  int base = blockIdx.x * 128 + wave * 32;

  s16x8 A[2][2];
  #pragma unroll
  for (int rt = 0; rt < 2; ++rt) {
    int row = base + rt * 16 + lr;
    #pragma unroll
    for (int kh = 0; kh < 2; ++kh) {
      const float4* zp = reinterpret_cast<const float4*>(
          z + (size_t)row * D64 + kh * 32 + lg * 8);
      float4 p0 = zp[0], p1 = zp[1];
      s16x8 t;
      t[0] = f2bf(p0.x); t[1] = f2bf(p0.y); t[2] = f2bf(p0.z); t[3] = f2bf(p0.w);
      t[4] = f2bf(p1.x); t[5] = f2bf(p1.y); t[6] = f2bf(p1.z); t[7] = f2bf(p1.w);
      A[rt][kh] = t;
    }
  }

  float thr[2][4];
  float maxthr = -INFINITY;
  #pragma unroll
  for (int rt = 0; rt < 2; ++rt)
    #pragma unroll
    for (int r = 0; r < 4; ++r) {
      thr[rt][r] = pmin[base + rt * 16 + lg * 4 + r] + CBAND;
      maxthr = fmaxf(maxthr, thr[rt][r]);
    }

  const s16x8* bp = reinterpret_cast<const s16x8*>(cbh) + (size_t)lr * 8 + lg;
  const float* cqp = csq + lr;
  int niter = K / 16;

  #pragma unroll 2
  for (int t2 = 0; t2 < niter; ++t2) {
    s16x8 B0 = bp[0];
    s16x8 B1 = bp[4];
    float cq = *cqp;
    bp += 128;
    cqp += 16;
    float s[2][4];
    #pragma unroll
    for (int rt = 0; rt < 2; ++rt) {
      f32x4 acc = {0.f, 0.f, 0.f, 0.f};
      acc = __builtin_amdgcn_mfma_f32_16x16x32_bf16(A[rt][0], B0, acc, 0, 0, 0);
      acc = __builtin_amdgcn_mfma_f32_16x16x32_bf16(A[rt][1], B1, acc, 0, 0, 0);
      #pragma unroll
      for (int r = 0; r < 4; ++r)
        s[rt][r] = fmaf(-2.0f, acc[r], cq);
    }
    float smin = fminf(
        fminf(fminf(s[0][0], s[0][1]), fminf(s[0][2], s[0][3])),
        fminf(fminf(s[1][0], s[1][1]), fminf(s[1][2], s[1][3])));
    if (__any(smin <= maxthr)) {
      int k = t2 * 16 + lr;
      #pragma unroll
      for (int rt = 0; rt < 2; ++rt)
        #pragma unroll
        for (int r = 0; r < 4; ++r) {
          if (s[rt][r] <= thr[rt][r]) {
            int n = base + rt * 16 + lg * 4 + r;
            unsigned slot = atomicAdd(&pcnt[n], 1u);
            if (slot < NSLOT) cand[(size_t)n * NSLOT + slot] = k;
          }
        }
    }
  }
}

// ---------------- exact fp32 rescore of candidates + fp64 tiebreak ----------------
__global__ __launch_bounds__(256) void rescore_assign_kernel(
    const float* __restrict__ z, const float* __restrict__ cb,
    const float* __restrict__ csq,
    const unsigned int* __restrict__ pcnt, const int* __restrict__ cand,
    const int* __restrict__ batch_raw,
    int* __restrict__ fidx, float* __restrict__ out_idx,
    unsigned int* __restrict__ counts, int N, int K) {
  int n = blockIdx.x * blockDim.x + threadIdx.x;
  if (n >= N) return;
  int cnt = min(pcnt[n], (unsigned)NSLOT);

  const float4* z4 = reinterpret_cast<const float4*>(z) + (size_t)n * 16;
  float4 zr[16];
  #pragma unroll
  for (int d = 0; d < 16; ++d) zr[d] = z4[d];

  float b1 = INFINITY, b2 = INFINITY;
  int i1 = 0x7FFFFFFF, i2 = 0x7FFFFFFF;
  for (int c = 0; c < cnt; ++c) {
    int k = cand[(size_t)n * NSLOT + c];
    const float4* cr = reinterpret_cast<const float4*>(cb) + (size_t)k * 16;
    float4 a = {0.f, 0.f, 0.f, 0.f};
    #pragma unroll
    for (int d = 0; d < 16; ++d) {
      float4 q = cr[d], zz = zr[d];
      a.x = fmaf(q.x, zz.x, a.x);
      a.y = fmaf(q.y, zz.y, a.y);
      a.z = fmaf(q.z, zz.z, a.z);
      a.w = fmaf(q.w, zz.w, a.w);
    }
    float s = csq[k] - 2.0f * ((a.x + a.y) + (a.z + a.w));
    // top-2 with (score, index) ordering (candidates arrive unordered)
    bool bet1 = (s < b1) || (s == b1 && k < i1);
    float cs = bet1 ? b1 : s;  int ci = bet1 ? i1 : k;
    b1 = bet1 ? s : b1;        i1 = bet1 ? k : i1;
    bool bet2 = (cs < b2) || (cs == b2 && ci < i2);
    b2 = bet2 ? cs : b2;       i2 = bet2 ? ci : i2;
  }

  int final_i = i1;
  if (cnt >= 2 && (b2 - b1) < 1e-3f) {
    const float* zp  = z  + (size_t)n  * D64;
    const float* c1p = cb + (size_t)i1 * D64;
    const float* c2p = cb + (size_t)i2 * D64;
    double d0 = 0.0, d1 = 0.0;
    for (int d = 0; d < D64; ++d) {
      double t0 = (double)zp[d] - (double)c1p[d];
      double t1 = (double)zp[d] - (double)c2p[d];
      d0 += t0 * t0;
      d1 += t1 * t1;
    }
    if (d1 < d0 || (d1 == d0 && i2 < i1)) final_i = i2;
  }

  fidx[n] = final_i;
  out_idx[n] = (float)final_i;

  int is64 = (batch_raw[N - 1] == 0) ? 1 : 0;
  int b = is64 ? batch_raw[2 * n] : batch_raw[n];
  atomicAdd(&counts[(size_t)b * K + final_i], 1u);
}

// ---------------- gather + straight-through + SSE ----------------
__global__ __launch_bounds__(256) void quant_kernel(
    const float* __restrict__ z, const float* __restrict__ cb,
    const int* __restrict__ fidx, float* __restrict__ outq,
    double* __restrict__ sse, int N) {
  __shared__ double red[4];
  int g = blockIdx.x * blockDim.x + threadIdx.x;
  int total4 = N * 16;
  double local = 0.0;
  if (g < total4) {
    int n = g >> 4, d4 = g & 15;
    int k = fidx[n];
    float4 zz = reinterpret_cast<const float4*>(z)[g];
    float4 qq = reinterpret_cast<const float4*>(cb)[(size_t)k * 16 + d4];
    float4 t = {qq.x - zz.x, qq.y - zz.y, qq.z - zz.z, qq.w - zz.w};
    float4 st = {zz.x + t.x, zz.y + t.y, zz.z + t.z, zz.w + t.w};
    reinterpret_cast<float4*>(outq)[g] = st;
    local = (double)t.x * t.x + (double)t.y * t.y +
            (double)t.z * t.z + (double)t.w * t.w;
  }
  #pragma unroll
  for (int off = 32; off; off >>= 1) local += __shfl_xor(local, off, 64);
  int lane = threadIdx.x & 63, w = threadIdx.x >> 6;
  if (lane == 0) red[w] = local;
  __syncthreads();
  if (threadIdx.x == 0) atomicAdd(sse, red[0] + red[1] + red[2] + red[3]);
}

// ---------------- per-batch entropy / perplexity / unique ----------------
__global__ __launch_bounds__(256) void stats_kernel(
    const unsigned int* __restrict__ counts,
    double* __restrict__ perp, double* __restrict__ ent,
    double* __restrict__ uniq, int K) {
  __shared__ double sh4[4], she[4], shu[4];
  int b = blockIdx.x;
  const unsigned int* c = counts + (size_t)b * K;
  int lane = threadIdx.x & 63, w = threadIdx.x >> 6;

  double tot = 0.0;
  for (int k = threadIdx.x; k < K; k += blockDim.x) tot += (double)c[k];
  #pragma unroll
  for (int off = 32; off; off >>= 1) tot += __shfl_xor(tot, off, 64);
  if (lane == 0) sh4[w] = tot;
  __syncthreads();
  double total = sh4[0] + sh4[1] + sh4[2] + sh4[3];
  double denom = fmax(total, 1.0);

  double e = 0.0, u = 0.0;
  for (int k = threadIdx.x; k < K; k += blockDim.x) {
    double cc = (double)c[k];
    double p = cc / denom;
    e -= p * log(p + 1e-10);
    if (cc > 0.0) u += 1.0;
  }
  #pragma unroll
  for (int off = 32; off; off >>= 1) {
    e += __shfl_xor(e, off, 64);
    u += __shfl_xor(u, off, 64);
  }
  if (lane == 0) { she[w] = e; shu[w] = u; }
  __syncthreads();
  if (threadIdx.x == 0) {
    double E = she[0] + she[1] + she[2] + she[3];
    double U = shu[0] + shu[1] + shu[2] + shu[3];
    ent[b] = E; perp[b] = exp(E); uniq[b] = U;
  }
}

// ---------------- finalize scalars ----------------
__global__ void final_kernel(const double* __restrict__ sse,
                             const double* __restrict__ perp,
                             const double* __restrict__ ent,
                             const double* __restrict__ uniq,
                             float* __restrict__ out, int N) {
  if (threadIdx.x == 0 && blockIdx.x == 0) {
    double mp = 0.0, me = 0.0, mu = 0.0;
    for (int b = 0; b < NBATCH; ++b) { mp += perp[b]; me += ent[b]; mu += uniq[b]; }
    mp /= NBATCH; me /= NBATCH; mu /= NBATCH;
    double loss = *sse / ((double)N * (double)D64);
    size_t voff = (size_t)N * D64;
    size_t coff = voff + 1;
    size_t poff = coff + 1 + (size_t)N;
    out[voff] = (float)loss;
    out[coff] = (float)loss;
    out[poff] = (float)mp;
    out[poff + 1] = (float)me;
    out[poff + 2] = (float)mu;
  }
}

extern "C" void kernel_launch(void* const* d_in, const int* in_sizes, int n_in,
                              void* d_out, int out_size, void* d_ws, size_t ws_size,
                              hipStream_t stream) {
  const float* z = (const float*)d_in[0];
  const int* bid = (const int*)d_in[1];
  const float* cb = (const float*)d_in[2];
  int N = in_sizes[1];
  int Dd = in_sizes[0] / N;
  int K = in_sizes[2] / Dd;
  float* out = (float*)d_out;

  // workspace layout (256B-aligned chunks)
  char* ws = (char*)d_ws;
  size_t off = 0;
  auto alloc = [&](size_t bytes) {
    void* p = ws + off;
    off += (bytes + 255) & ~(size_t)255;
    return p;
  };
  unsigned int* counts = (unsigned int*)alloc((size_t)NBATCH * K * 4);
  double* sse  = (double*)alloc(8);
  double* perp = (double*)alloc(8 * NBATCH);
  double* ent  = (double*)alloc(8 * NBATCH);
  double* uniq = (double*)alloc(8 * NBATCH);
  float* csq = (float*)alloc((size_t)K * 4);
  short* cbh = (short*)alloc((size_t)K * D64 * 2);
  float* pmin = (float*)alloc((size_t)N * 4);
  unsigned int* pcnt = (unsigned int*)alloc((size_t)N * 4);
  int* cand = (int*)alloc((size_t)N * NSLOT * 4);
  int* fidx = (int*)alloc((size_t)N * 4);

  (void)hipMemsetAsync(counts, 0, (size_t)NBATCH * K * 4, stream);
  (void)hipMemsetAsync(sse, 0, 8, stream);
  (void)hipMemsetAsync(pcnt, 0, (size_t)N * 4, stream);

  size_t ioff = (size_t)N * Dd + 2;

  csq_cvt_kernel<<<(K * 64 + 255) / 256, 256, 0, stream>>>(cb, csq, cbh, K);
  filter_min_kernel<<<N / 128, 256, 0, stream>>>(z, cbh, csq, pmin, N, K);
  emit_kernel<<<N / 128, 256, 0, stream>>>(z, cbh, csq, pmin, pcnt, cand, N, K);
  rescore_assign_kernel<<<(N + 255) / 256, 256, 0, stream>>>(
      z, cb, csq, pcnt, cand, bid, fidx, out + ioff, counts, N, K);
  quant_kernel<<<(N * 16 + 255) / 256, 256, 0, stream>>>(z, cb, fidx, out, sse, N);
  stats_kernel<<<NBATCH, 256, 0, stream>>>(counts, perp, ent, uniq, K);
  final_kernel<<<1, 64, 0, stream>>>(sse, perp, ent, uniq, out, N);
}

// Round 5
// 673.080 us; speedup vs baseline: 3.1065x; 1.0102x over previous
//
#include <hip/hip_runtime.h>
#include <math.h>

#define D64 64
#define NBATCH 8
#define CBAND 2.0f
#define NSLOT 16
#define KSPL 4

typedef short s16x8 __attribute__((ext_vector_type(8)));   // 8 bf16 (bit pattern)
typedef float f32x4 __attribute__((ext_vector_type(4)));

__device__ inline short f2bf(float f) {
  unsigned u = __builtin_bit_cast(unsigned, f);
  unsigned r = (u + 0x7FFFu + ((u >> 16) & 1u)) >> 16;
  return (short)r;
}

// order-preserving float <-> uint (for atomicMin)
__device__ inline unsigned pack32(float s) {
  unsigned u = __builtin_bit_cast(unsigned, s);
  return (u & 0x80000000u) ? ~u : (u | 0x80000000u);
}
__device__ inline float unpack32(unsigned u) {
  unsigned b = (u & 0x80000000u) ? (u ^ 0x80000000u) : ~u;
  return __builtin_bit_cast(float, b);
}

// ---------------- c_sq + bf16 convert ----------------
__global__ __launch_bounds__(256) void csq_cvt_kernel(
    const float* __restrict__ cb, float* __restrict__ csq,
    short* __restrict__ cbh, int K) {
  int t = blockIdx.x * blockDim.x + threadIdx.x;
  int row = t >> 6, lane = t & 63;
  if (row >= K) return;
  float v = cb[(size_t)row * D64 + lane];
  cbh[(size_t)row * D64 + lane] = f2bf(v);
  v *= v;
  #pragma unroll
  for (int off = 32; off; off >>= 1) v += __shfl_xor(v, off, 64);
  if (lane == 0) csq[row] = v;
}

// ---------------- MFMA pass A: per-point bf16-score min over a K-split ----------------
// wave = 32 points (2 row-tiles of 16), block = 4 waves = 128 points.
__global__ __launch_bounds__(256) void filter_min_kernel(
    const float* __restrict__ z, const short* __restrict__ cbh,
    const float* __restrict__ csq, unsigned* __restrict__ pmin, int N, int K) {
  int wave = threadIdx.x >> 6;
  int l = threadIdx.x & 63;
  int lr = l & 15, lg = l >> 4;
  int base = blockIdx.x * 128 + wave * 32;
  int k0 = blockIdx.y * (K / KSPL);

  s16x8 A[2][2];
  #pragma unroll
  for (int rt = 0; rt < 2; ++rt) {
    int row = base + rt * 16 + lr;
    #pragma unroll
    for (int kh = 0; kh < 2; ++kh) {
      const float4* zp = reinterpret_cast<const float4*>(
          z + (size_t)row * D64 + kh * 32 + lg * 8);
      float4 p0 = zp[0], p1 = zp[1];
      s16x8 t;
      t[0] = f2bf(p0.x); t[1] = f2bf(p0.y); t[2] = f2bf(p0.z); t[3] = f2bf(p0.w);
      t[4] = f2bf(p1.x); t[5] = f2bf(p1.y); t[6] = f2bf(p1.z); t[7] = f2bf(p1.w);
      A[rt][kh] = t;
    }
  }

  float rmin[2][4];
  #pragma unroll
  for (int rt = 0; rt < 2; ++rt)
    #pragma unroll
    for (int r = 0; r < 4; ++r) rmin[rt][r] = INFINITY;

  const s16x8* bp = reinterpret_cast<const s16x8*>(cbh) + (size_t)k0 * 8 +
                    (size_t)lr * 8 + lg;
  const float* cqp = csq + k0 + lr;
  int niter = K / KSPL / 16;

  #pragma unroll 8
  for (int t2 = 0; t2 < niter; ++t2) {
    s16x8 B0 = bp[0];
    s16x8 B1 = bp[4];
    float cq = *cqp;
    bp += 128;       // 16 codes * 8 frags
    cqp += 16;
    #pragma unroll
    for (int rt = 0; rt < 2; ++rt) {
      f32x4 acc = {0.f, 0.f, 0.f, 0.f};
      acc = __builtin_amdgcn_mfma_f32_16x16x32_bf16(A[rt][0], B0, acc, 0, 0, 0);
      acc = __builtin_amdgcn_mfma_f32_16x16x32_bf16(A[rt][1], B1, acc, 0, 0, 0);
      #pragma unroll
      for (int r = 0; r < 4; ++r) {
        float s = fmaf(-2.0f, acc[r], cq);
        rmin[rt][r] = fminf(rmin[rt][r], s);
      }
    }
  }

  // reduce over the 16 cols (lane bits 0..3), merge via atomicMin
  #pragma unroll
  for (int rt = 0; rt < 2; ++rt)
    #pragma unroll
    for (int r = 0; r < 4; ++r) {
      float v = rmin[rt][r];
      v = fminf(v, __shfl_xor(v, 1, 64));
      v = fminf(v, __shfl_xor(v, 2, 64));
      v = fminf(v, __shfl_xor(v, 4, 64));
      v = fminf(v, __shfl_xor(v, 8, 64));
      if (lr == 0)
        atomicMin(&pmin[base + rt * 16 + lg * 4 + r], pack32(v));
    }
}

// ---------------- MFMA pass B: emit candidate codes within band ----------------
__global__ __launch_bounds__(256) void emit_kernel(
    const float* __restrict__ z, const short* __restrict__ cbh,
    const float* __restrict__ csq, const unsigned* __restrict__ pmin,
    unsigned int* __restrict__ pcnt, int* __restrict__ cand, int N, int K) {
  int wave = threadIdx.x >> 6;
  int l = threadIdx.x & 63;
  int lr = l & 15, lg = l >> 4;
  int base = blockIdx.x * 128 + wave * 32;
  int k0 = blockIdx.y * (K / KSPL);

  s16x8 A[2][2];
  #pragma unroll
  for (int rt = 0; rt < 2; ++rt) {
    int row = base + rt * 16 + lr;
    #pragma unroll
    for (int kh = 0; kh < 2; ++kh) {
      const float4* zp = reinterpret_cast<const float4*>(
          z + (size_t)row * D64 + kh * 32 + lg * 8);
      float4 p0 = zp[0], p1 = zp[1];
      s16x8 t;
      t[0] = f2bf(p0.x); t[1] = f2bf(p0.y); t[2] = f2bf(p0.z); t[3] = f2bf(p0.w);
      t[4] = f2bf(p1.x); t[5] = f2bf(p1.y); t[6] = f2bf(p1.z); t[7] = f2bf(p1.w);
      A[rt][kh] = t;
    }
  }

  float thr[2][4];
  float maxthr = -INFINITY;
  #pragma unroll
  for (int rt = 0; rt < 2; ++rt)
    #pragma unroll
    for (int r = 0; r < 4; ++r) {
      thr[rt][r] = unpack32(pmin[base + rt * 16 + lg * 4 + r]) + CBAND;
      maxthr = fmaxf(maxthr, thr[rt][r]);
    }

  const s16x8* bp = reinterpret_cast<const s16x8*>(cbh) + (size_t)k0 * 8 +
                    (size_t)lr * 8 + lg;
  const float* cqp = csq + k0 + lr;
  int niter = K / KSPL / 16;

  #pragma unroll 4
  for (int t2 = 0; t2 < niter; ++t2) {
    s16x8 B0 = bp[0];
    s16x8 B1 = bp[4];
    float cq = *cqp;
    bp += 128;
    cqp += 16;
    float s[2][4];
    #pragma unroll
    for (int rt = 0; rt < 2; ++rt) {
      f32x4 acc = {0.f, 0.f, 0.f, 0.f};
      acc = __builtin_amdgcn_mfma_f32_16x16x32_bf16(A[rt][0], B0, acc, 0, 0, 0);
      acc = __builtin_amdgcn_mfma_f32_16x16x32_bf16(A[rt][1], B1, acc, 0, 0, 0);
      #pragma unroll
      for (int r = 0; r < 4; ++r)
        s[rt][r] = fmaf(-2.0f, acc[r], cq);
    }
    float smin = fminf(
        fminf(fminf(s[0][0], s[0][1]), fminf(s[0][2], s[0][3])),
        fminf(fminf(s[1][0], s[1][1]), fminf(s[1][2], s[1][3])));
    if (__any(smin <= maxthr)) {
      int k = k0 + t2 * 16 + lr;
      #pragma unroll
      for (int rt = 0; rt < 2; ++rt)
        #pragma unroll
        for (int r = 0; r < 4; ++r) {
          if (s[rt][r] <= thr[rt][r]) {
            int n = base + rt * 16 + lg * 4 + r;
            unsigned slot = atomicAdd(&pcnt[n], 1u);
            if (slot < NSLOT) cand[(size_t)n * NSLOT + slot] = k;
          }
        }
    }
  }
}

// ---------------- exact fp32 rescore of candidates + fp64 tiebreak ----------------
__global__ __launch_bounds__(256) void rescore_assign_kernel(
    const float* __restrict__ z, const float* __restrict__ cb,
    const float* __restrict__ csq,
    const unsigned int* __restrict__ pcnt, const int* __restrict__ cand,
    const int* __restrict__ batch_raw,
    int* __restrict__ fidx, float* __restrict__ out_idx,
    unsigned int* __restrict__ counts, int N, int K) {
  int n = blockIdx.x * blockDim.x + threadIdx.x;
  if (n >= N) return;
  int cnt = min(pcnt[n], (unsigned)NSLOT);

  const float4* z4 = reinterpret_cast<const float4*>(z) + (size_t)n * 16;
  float4 zr[16];
  #pragma unroll
  for (int d = 0; d < 16; ++d) zr[d] = z4[d];

  float b1 = INFINITY, b2 = INFINITY;
  int i1 = 0x7FFFFFFF, i2 = 0x7FFFFFFF;
  for (int c = 0; c < cnt; ++c) {
    int k = cand[(size_t)n * NSLOT + c];
    const float4* cr = reinterpret_cast<const float4*>(cb) + (size_t)k * 16;
    float4 a = {0.f, 0.f, 0.f, 0.f};
    #pragma unroll
    for (int d = 0; d < 16; ++d) {
      float4 q = cr[d], zz = zr[d];
      a.x = fmaf(q.x, zz.x, a.x);
      a.y = fmaf(q.y, zz.y, a.y);
      a.z = fmaf(q.z, zz.z, a.z);
      a.w = fmaf(q.w, zz.w, a.w);
    }
    float s = csq[k] - 2.0f * ((a.x + a.y) + (a.z + a.w));
    // top-2 with (score, index) ordering (candidates arrive unordered)
    bool bet1 = (s < b1) || (s == b1 && k < i1);
    float cs = bet1 ? b1 : s;  int ci = bet1 ? i1 : k;
    b1 = bet1 ? s : b1;        i1 = bet1 ? k : i1;
    bool bet2 = (cs < b2) || (cs == b2 && ci < i2);
    b2 = bet2 ? cs : b2;       i2 = bet2 ? ci : i2;
  }

  int final_i = i1;
  if (cnt >= 2 && (b2 - b1) < 1e-3f) {
    const float* zp  = z  + (size_t)n  * D64;
    const float* c1p = cb + (size_t)i1 * D64;
    const float* c2p = cb + (size_t)i2 * D64;
    double d0 = 0.0, d1 = 0.0;
    for (int d = 0; d < D64; ++d) {
      double t0 = (double)zp[d] - (double)c1p[d];
      double t1 = (double)zp[d] - (double)c2p[d];
      d0 += t0 * t0;
      d1 += t1 * t1;
    }
    if (d1 < d0 || (d1 == d0 && i2 < i1)) final_i = i2;
  }

  fidx[n] = final_i;
  out_idx[n] = (float)final_i;

  int is64 = (batch_raw[N - 1] == 0) ? 1 : 0;
  int b = is64 ? batch_raw[2 * n] : batch_raw[n];
  atomicAdd(&counts[(size_t)b * K + final_i], 1u);
}

// ---------------- gather + straight-through + SSE ----------------
__global__ __launch_bounds__(256) void quant_kernel(
    const float* __restrict__ z, const float* __restrict__ cb,
    const int* __restrict__ fidx, float* __restrict__ outq,
    double* __restrict__ sse, int N) {
  __shared__ double red[4];
  int g = blockIdx.x * blockDim.x + threadIdx.x;
  int total4 = N * 16;
  double local = 0.0;
  if (g < total4) {
    int n = g >> 4, d4 = g & 15;
    int k = fidx[n];
    float4 zz = reinterpret_cast<const float4*>(z)[g];
    float4 qq = reinterpret_cast<const float4*>(cb)[(size_t)k * 16 + d4];
    float4 t = {qq.x - zz.x, qq.y - zz.y, qq.z - zz.z, qq.w - zz.w};
    float4 st = {zz.x + t.x, zz.y + t.y, zz.z + t.z, zz.w + t.w};
    reinterpret_cast<float4*>(outq)[g] = st;
    local = (double)t.x * t.x + (double)t.y * t.y +
            (double)t.z * t.z + (double)t.w * t.w;
  }
  #pragma unroll
  for (int off = 32; off; off >>= 1) local += __shfl_xor(local, off, 64);
  int lane = threadIdx.x & 63, w = threadIdx.x >> 6;
  if (lane == 0) red[w] = local;
  __syncthreads();
  if (threadIdx.x == 0) atomicAdd(sse, red[0] + red[1] + red[2] + red[3]);
}

// ---------------- per-batch entropy / perplexity / unique ----------------
__global__ __launch_bounds__(256) void stats_kernel(
    const unsigned int* __restrict__ counts,
    double* __restrict__ perp, double* __restrict__ ent,
    double* __restrict__ uniq, int K) {
  __shared__ double sh4[4], she[4], shu[4];
  int b = blockIdx.x;
  const unsigned int* c = counts + (size_t)b * K;
  int lane = threadIdx.x & 63, w = threadIdx.x >> 6;

  double tot = 0.0;
  for (int k = threadIdx.x; k < K; k += blockDim.x) tot += (double)c[k];
  #pragma unroll
  for (int off = 32; off; off >>= 1) tot += __shfl_xor(tot, off, 64);
  if (lane == 0) sh4[w] = tot;
  __syncthreads();
  double total = sh4[0] + sh4[1] + sh4[2] + sh4[3];
  double denom = fmax(total, 1.0);

  double e = 0.0, u = 0.0;
  for (int k = threadIdx.x; k < K; k += blockDim.x) {
    double cc = (double)c[k];
    double p = cc / denom;
    e -= p * log(p + 1e-10);
    if (cc > 0.0) u += 1.0;
  }
  #pragma unroll
  for (int off = 32; off; off >>= 1) {
    e += __shfl_xor(e, off, 64);
    u += __shfl_xor(u, off, 64);
  }
  if (lane == 0) { she[w] = e; shu[w] = u; }
  __syncthreads();
  if (threadIdx.x == 0) {
    double E = she[0] + she[1] + she[2] + she[3];
    double U = shu[0] + shu[1] + shu[2] + shu[3];
    ent[b] = E; perp[b] = exp(E); uniq[b] = U;
  }
}

// ---------------- finalize scalars ----------------
__global__ void final_kernel(const double* __restrict__ sse,
                             const double* __restrict__ perp,
                             const double* __restrict__ ent,
                             const double* __restrict__ uniq,
                             float* __restrict__ out, int N) {
  if (threadIdx.x == 0 && blockIdx.x == 0) {
    double mp = 0.0, me = 0.0, mu = 0.0;
    for (int b = 0; b < NBATCH; ++b) { mp += perp[b]; me += ent[b]; mu += uniq[b]; }
    mp /= NBATCH; me /= NBATCH; mu /= NBATCH;
    double loss = *sse / ((double)N * (double)D64);
    size_t voff = (size_t)N * D64;
    size_t coff = voff + 1;
    size_t poff = coff + 1 + (size_t)N;
    out[voff] = (float)loss;
    out[coff] = (float)loss;
    out[poff] = (float)mp;
    out[poff + 1] = (float)me;
    out[poff + 2] = (float)mu;
  }
}

extern "C" void kernel_launch(void* const* d_in, const int* in_sizes, int n_in,
                              void* d_out, int out_size, void* d_ws, size_t ws_size,
                              hipStream_t stream) {
  const float* z = (const float*)d_in[0];
  const int* bid = (const int*)d_in[1];
  const float* cb = (const float*)d_in[2];
  int N = in_sizes[1];
  int Dd = in_sizes[0] / N;
  int K = in_sizes[2] / Dd;
  float* out = (float*)d_out;

  // workspace layout (256B-aligned chunks)
  char* ws = (char*)d_ws;
  size_t off = 0;
  auto alloc = [&](size_t bytes) {
    void* p = ws + off;
    off += (bytes + 255) & ~(size_t)255;
    return p;
  };
  unsigned int* counts = (unsigned int*)alloc((size_t)NBATCH * K * 4);
  double* sse  = (double*)alloc(8);
  double* perp = (double*)alloc(8 * NBATCH);
  double* ent  = (double*)alloc(8 * NBATCH);
  double* uniq = (double*)alloc(8 * NBATCH);
  float* csq = (float*)alloc((size_t)K * 4);
  short* cbh = (short*)alloc((size_t)K * D64 * 2);
  unsigned* pmin = (unsigned*)alloc((size_t)N * 4);
  unsigned int* pcnt = (unsigned int*)alloc((size_t)N * 4);
  int* cand = (int*)alloc((size_t)N * NSLOT * 4);
  int* fidx = (int*)alloc((size_t)N * 4);

  (void)hipMemsetAsync(counts, 0, (size_t)NBATCH * K * 4, stream);
  (void)hipMemsetAsync(sse, 0, 8, stream);
  (void)hipMemsetAsync(pcnt, 0, (size_t)N * 4, stream);
  (void)hipMemsetAsync(pmin, 0xFF, (size_t)N * 4, stream);   // +inf packed

  size_t ioff = (size_t)N * Dd + 2;

  csq_cvt_kernel<<<(K * 64 + 255) / 256, 256, 0, stream>>>(cb, csq, cbh, K);
  dim3 fg(N / 128, KSPL);
  filter_min_kernel<<<fg, 256, 0, stream>>>(z, cbh, csq, pmin, N, K);
  emit_kernel<<<fg, 256, 0, stream>>>(z, cbh, csq, pmin, pcnt, cand, N, K);
  rescore_assign_kernel<<<(N + 255) / 256, 256, 0, stream>>>(
      z, cb, csq, pcnt, cand, bid, fidx, out + ioff, counts, N, K);
  quant_kernel<<<(N * 16 + 255) / 256, 256, 0, stream>>>(z, cb, fidx, out, sse, N);
  stats_kernel<<<NBATCH, 256, 0, stream>>>(counts, perp, ent, uniq, K);
  final_kernel<<<1, 64, 0, stream>>>(sse, perp, ent, uniq, out, N);
}

// Round 6
// 637.949 us; speedup vs baseline: 3.2776x; 1.0551x over previous
//
#include <hip/hip_runtime.h>
#include <math.h>

#define D64 64
#define NBATCH 8
#define CBAND 2.0f
#define NSLOT 16
#define KSPL 8

typedef short s16x8 __attribute__((ext_vector_type(8)));   // 8 bf16 (bit pattern)
typedef float f32x4 __attribute__((ext_vector_type(4)));

__device__ inline short f2bf(float f) {
  unsigned u = __builtin_bit_cast(unsigned, f);
  unsigned r = (u + 0x7FFFu + ((u >> 16) & 1u)) >> 16;
  return (short)r;
}

// order-preserving float <-> uint (for atomicMin)
__device__ inline unsigned pack32(float s) {
  unsigned u = __builtin_bit_cast(unsigned, s);
  return (u & 0x80000000u) ? ~u : (u | 0x80000000u);
}
__device__ inline float unpack32(unsigned u) {
  unsigned b = (u & 0x80000000u) ? (u ^ 0x80000000u) : ~u;
  return __builtin_bit_cast(float, b);
}

// ---------------- c_sq + bf16 convert ----------------
__global__ __launch_bounds__(256) void csq_cvt_kernel(
    const float* __restrict__ cb, float* __restrict__ csq,
    short* __restrict__ cbh, int K) {
  int t = blockIdx.x * blockDim.x + threadIdx.x;
  int row = t >> 6, lane = t & 63;
  if (row >= K) return;
  float v = cb[(size_t)row * D64 + lane];
  cbh[(size_t)row * D64 + lane] = f2bf(v);
  v *= v;
  #pragma unroll
  for (int off = 32; off; off >>= 1) v += __shfl_xor(v, off, 64);
  if (lane == 0) csq[row] = v;
}

// ---------------- MFMA pass A: per-point bf16-score min over a K-split ----------------
// wave = 32 points (2 row-tiles of 16), block = 4 waves = 128 points.
__global__ __launch_bounds__(256, 8) void filter_min_kernel(
    const float* __restrict__ z, const short* __restrict__ cbh,
    const float* __restrict__ csq, unsigned* __restrict__ pmin, int N, int K) {
  int wave = threadIdx.x >> 6;
  int l = threadIdx.x & 63;
  int lr = l & 15, lg = l >> 4;
  int base = blockIdx.x * 128 + wave * 32;
  int k0 = blockIdx.y * (K / KSPL);

  s16x8 A[2][2];
  #pragma unroll
  for (int rt = 0; rt < 2; ++rt) {
    int row = base + rt * 16 + lr;
    #pragma unroll
    for (int kh = 0; kh < 2; ++kh) {
      const float4* zp = reinterpret_cast<const float4*>(
          z + (size_t)row * D64 + kh * 32 + lg * 8);
      float4 p0 = zp[0], p1 = zp[1];
      s16x8 t;
      t[0] = f2bf(p0.x); t[1] = f2bf(p0.y); t[2] = f2bf(p0.z); t[3] = f2bf(p0.w);
      t[4] = f2bf(p1.x); t[5] = f2bf(p1.y); t[6] = f2bf(p1.z); t[7] = f2bf(p1.w);
      A[rt][kh] = t;
    }
  }

  float rmin[2][4];
  #pragma unroll
  for (int rt = 0; rt < 2; ++rt)
    #pragma unroll
    for (int r = 0; r < 4; ++r) rmin[rt][r] = INFINITY;

  const s16x8* bp = reinterpret_cast<const s16x8*>(cbh) + (size_t)k0 * 8 +
                    (size_t)lr * 8 + lg;
  const float* cqp = csq + k0 + lr;
  int niter = K / KSPL / 16;

  // depth-2 register prefetch (final-iter over-read stays inside ws)
  s16x8 B0 = bp[0];
  s16x8 B1 = bp[4];
  float cq = *cqp;

  #pragma unroll 4
  for (int t2 = 0; t2 < niter; ++t2) {
    bp += 128;       // 16 codes * 8 frags
    cqp += 16;
    s16x8 B0n = bp[0];
    s16x8 B1n = bp[4];
    float cqn = *cqp;
    #pragma unroll
    for (int rt = 0; rt < 2; ++rt) {
      f32x4 acc = {0.f, 0.f, 0.f, 0.f};
      acc = __builtin_amdgcn_mfma_f32_16x16x32_bf16(A[rt][0], B0, acc, 0, 0, 0);
      acc = __builtin_amdgcn_mfma_f32_16x16x32_bf16(A[rt][1], B1, acc, 0, 0, 0);
      #pragma unroll
      for (int r = 0; r < 4; ++r) {
        float s = fmaf(-2.0f, acc[r], cq);
        rmin[rt][r] = fminf(rmin[rt][r], s);
      }
    }
    B0 = B0n; B1 = B1n; cq = cqn;
  }

  // reduce over the 16 cols (lane bits 0..3), merge via atomicMin
  #pragma unroll
  for (int rt = 0; rt < 2; ++rt)
    #pragma unroll
    for (int r = 0; r < 4; ++r) {
      float v = rmin[rt][r];
      v = fminf(v, __shfl_xor(v, 1, 64));
      v = fminf(v, __shfl_xor(v, 2, 64));
      v = fminf(v, __shfl_xor(v, 4, 64));
      v = fminf(v, __shfl_xor(v, 8, 64));
      if (lr == 0)
        atomicMin(&pmin[base + rt * 16 + lg * 4 + r], pack32(v));
    }
}

// ---------------- MFMA pass B: emit candidate codes within band ----------------
__global__ __launch_bounds__(256, 8) void emit_kernel(
    const float* __restrict__ z, const short* __restrict__ cbh,
    const float* __restrict__ csq, const unsigned* __restrict__ pmin,
    unsigned int* __restrict__ pcnt, int* __restrict__ cand, int N, int K) {
  int wave = threadIdx.x >> 6;
  int l = threadIdx.x & 63;
  int lr = l & 15, lg = l >> 4;
  int base = blockIdx.x * 128 + wave * 32;
  int k0 = blockIdx.y * (K / KSPL);

  s16x8 A[2][2];
  #pragma unroll
  for (int rt = 0; rt < 2; ++rt) {
    int row = base + rt * 16 + lr;
    #pragma unroll
    for (int kh = 0; kh < 2; ++kh) {
      const float4* zp = reinterpret_cast<const float4*>(
          z + (size_t)row * D64 + kh * 32 + lg * 8);
      float4 p0 = zp[0], p1 = zp[1];
      s16x8 t;
      t[0] = f2bf(p0.x); t[1] = f2bf(p0.y); t[2] = f2bf(p0.z); t[3] = f2bf(p0.w);
      t[4] = f2bf(p1.x); t[5] = f2bf(p1.y); t[6] = f2bf(p1.z); t[7] = f2bf(p1.w);
      A[rt][kh] = t;
    }
  }

  float thr[2][4];
  #pragma unroll
  for (int rt = 0; rt < 2; ++rt)
    #pragma unroll
    for (int r = 0; r < 4; ++r)
      thr[rt][r] = unpack32(pmin[base + rt * 16 + lg * 4 + r]) + CBAND;

  const s16x8* bp = reinterpret_cast<const s16x8*>(cbh) + (size_t)k0 * 8 +
                    (size_t)lr * 8 + lg;
  const float* cqp = csq + k0 + lr;
  int niter = K / KSPL / 16;

  s16x8 B0 = bp[0];
  s16x8 B1 = bp[4];
  float cq = *cqp;

  #pragma unroll 2
  for (int t2 = 0; t2 < niter; ++t2) {
    bp += 128;
    cqp += 16;
    s16x8 B0n = bp[0];
    s16x8 B1n = bp[4];
    float cqn = *cqp;
    float s[2][4];
    #pragma unroll
    for (int rt = 0; rt < 2; ++rt) {
      f32x4 acc = {0.f, 0.f, 0.f, 0.f};
      acc = __builtin_amdgcn_mfma_f32_16x16x32_bf16(A[rt][0], B0, acc, 0, 0, 0);
      acc = __builtin_amdgcn_mfma_f32_16x16x32_bf16(A[rt][1], B1, acc, 0, 0, 0);
      #pragma unroll
      for (int r = 0; r < 4; ++r)
        s[rt][r] = fmaf(-2.0f, acc[r], cq);
    }
    // per-point hit bits (tight gate: each score vs ITS point's threshold)
    int hits = 0;
    #pragma unroll
    for (int rt = 0; rt < 2; ++rt)
      #pragma unroll
      for (int r = 0; r < 4; ++r)
        hits |= (s[rt][r] <= thr[rt][r]) ? (1 << (rt * 4 + r)) : 0;
    if (__any(hits != 0)) {
      int k = k0 + t2 * 16 + lr;
      #pragma unroll
      for (int rt = 0; rt < 2; ++rt)
        #pragma unroll
        for (int r = 0; r < 4; ++r) {
          if (hits & (1 << (rt * 4 + r))) {
            int n = base + rt * 16 + lg * 4 + r;
            unsigned slot = atomicAdd(&pcnt[n], 1u);
            if (slot < NSLOT) cand[(size_t)n * NSLOT + slot] = k;
          }
        }
    }
    B0 = B0n; B1 = B1n; cq = cqn;
  }
}

// ---------------- exact fp32 rescore of candidates + fp64 tiebreak ----------------
__global__ __launch_bounds__(256) void rescore_assign_kernel(
    const float* __restrict__ z, const float* __restrict__ cb,
    const float* __restrict__ csq,
    const unsigned int* __restrict__ pcnt, const int* __restrict__ cand,
    const int* __restrict__ batch_raw,
    int* __restrict__ fidx, float* __restrict__ out_idx,
    unsigned int* __restrict__ counts, int N, int K) {
  int n = blockIdx.x * blockDim.x + threadIdx.x;
  if (n >= N) return;
  int cnt = min(pcnt[n], (unsigned)NSLOT);

  const float4* z4 = reinterpret_cast<const float4*>(z) + (size_t)n * 16;
  float4 zr[16];
  #pragma unroll
  for (int d = 0; d < 16; ++d) zr[d] = z4[d];

  float b1 = INFINITY, b2 = INFINITY;
  int i1 = 0x7FFFFFFF, i2 = 0x7FFFFFFF;
  for (int c = 0; c < cnt; ++c) {
    int k = cand[(size_t)n * NSLOT + c];
    const float4* cr = reinterpret_cast<const float4*>(cb) + (size_t)k * 16;
    float4 a = {0.f, 0.f, 0.f, 0.f};
    #pragma unroll
    for (int d = 0; d < 16; ++d) {
      float4 q = cr[d], zz = zr[d];
      a.x = fmaf(q.x, zz.x, a.x);
      a.y = fmaf(q.y, zz.y, a.y);
      a.z = fmaf(q.z, zz.z, a.z);
      a.w = fmaf(q.w, zz.w, a.w);
    }
    float s = csq[k] - 2.0f * ((a.x + a.y) + (a.z + a.w));
    // top-2 with (score, index) ordering (candidates arrive unordered)
    bool bet1 = (s < b1) || (s == b1 && k < i1);
    float cs = bet1 ? b1 : s;  int ci = bet1 ? i1 : k;
    b1 = bet1 ? s : b1;        i1 = bet1 ? k : i1;
    bool bet2 = (cs < b2) || (cs == b2 && ci < i2);
    b2 = bet2 ? cs : b2;       i2 = bet2 ? ci : i2;
  }

  int final_i = i1;
  if (cnt >= 2 && (b2 - b1) < 1e-3f) {
    const float* zp  = z  + (size_t)n  * D64;
    const float* c1p = cb + (size_t)i1 * D64;
    const float* c2p = cb + (size_t)i2 * D64;
    double d0 = 0.0, d1 = 0.0;
    for (int d = 0; d < D64; ++d) {
      double t0 = (double)zp[d] - (double)c1p[d];
      double t1 = (double)zp[d] - (double)c2p[d];
      d0 += t0 * t0;
      d1 += t1 * t1;
    }
    if (d1 < d0 || (d1 == d0 && i2 < i1)) final_i = i2;
  }

  fidx[n] = final_i;
  out_idx[n] = (float)final_i;

  int is64 = (batch_raw[N - 1] == 0) ? 1 : 0;
  int b = is64 ? batch_raw[2 * n] : batch_raw[n];
  atomicAdd(&counts[(size_t)b * K + final_i], 1u);
}

// ---------------- gather + straight-through + SSE ----------------
__global__ __launch_bounds__(256) void quant_kernel(
    const float* __restrict__ z, const float* __restrict__ cb,
    const int* __restrict__ fidx, float* __restrict__ outq,
    double* __restrict__ sse, int N) {
  __shared__ double red[4];
  int g = blockIdx.x * blockDim.x + threadIdx.x;
  int total4 = N * 16;
  double local = 0.0;
  if (g < total4) {
    int n = g >> 4, d4 = g & 15;
    int k = fidx[n];
    float4 zz = reinterpret_cast<const float4*>(z)[g];
    float4 qq = reinterpret_cast<const float4*>(cb)[(size_t)k * 16 + d4];
    float4 t = {qq.x - zz.x, qq.y - zz.y, qq.z - zz.z, qq.w - zz.w};
    float4 st = {zz.x + t.x, zz.y + t.y, zz.z + t.z, zz.w + t.w};
    reinterpret_cast<float4*>(outq)[g] = st;
    local = (double)t.x * t.x + (double)t.y * t.y +
            (double)t.z * t.z + (double)t.w * t.w;
  }
  #pragma unroll
  for (int off = 32; off; off >>= 1) local += __shfl_xor(local, off, 64);
  int lane = threadIdx.x & 63, w = threadIdx.x >> 6;
  if (lane == 0) red[w] = local;
  __syncthreads();
  if (threadIdx.x == 0) atomicAdd(sse, red[0] + red[1] + red[2] + red[3]);
}

// ---------------- per-batch entropy / perplexity / unique ----------------
__global__ __launch_bounds__(256) void stats_kernel(
    const unsigned int* __restrict__ counts,
    double* __restrict__ perp, double* __restrict__ ent,
    double* __restrict__ uniq, int K) {
  __shared__ double sh4[4], she[4], shu[4];
  int b = blockIdx.x;
  const unsigned int* c = counts + (size_t)b * K;
  int lane = threadIdx.x & 63, w = threadIdx.x >> 6;

  double tot = 0.0;
  for (int k = threadIdx.x; k < K; k += blockDim.x) tot += (double)c[k];
  #pragma unroll
  for (int off = 32; off; off >>= 1) tot += __shfl_xor(tot, off, 64);
  if (lane == 0) sh4[w] = tot;
  __syncthreads();
  double total = sh4[0] + sh4[1] + sh4[2] + sh4[3];
  double denom = fmax(total, 1.0);

  double e = 0.0, u = 0.0;
  for (int k = threadIdx.x; k < K; k += blockDim.x) {
    double cc = (double)c[k];
    double p = cc / denom;
    e -= p * log(p + 1e-10);
    if (cc > 0.0) u += 1.0;
  }
  #pragma unroll
  for (int off = 32; off; off >>= 1) {
    e += __shfl_xor(e, off, 64);
    u += __shfl_xor(u, off, 64);
  }
  if (lane == 0) { she[w] = e; shu[w] = u; }
  __syncthreads();
  if (threadIdx.x == 0) {
    double E = she[0] + she[1] + she[2] + she[3];
    double U = shu[0] + shu[1] + shu[2] + shu[3];
    ent[b] = E; perp[b] = exp(E); uniq[b] = U;
  }
}

// ---------------- finalize scalars ----------------
__global__ void final_kernel(const double* __restrict__ sse,
                             const double* __restrict__ perp,
                             const double* __restrict__ ent,
                             const double* __restrict__ uniq,
                             float* __restrict__ out, int N) {
  if (threadIdx.x == 0 && blockIdx.x == 0) {
    double mp = 0.0, me = 0.0, mu = 0.0;
    for (int b = 0; b < NBATCH; ++b) { mp += perp[b]; me += ent[b]; mu += uniq[b]; }
    mp /= NBATCH; me /= NBATCH; mu /= NBATCH;
    double loss = *sse / ((double)N * (double)D64);
    size_t voff = (size_t)N * D64;
    size_t coff = voff + 1;
    size_t poff = coff + 1 + (size_t)N;
    out[voff] = (float)loss;
    out[coff] = (float)loss;
    out[poff] = (float)mp;
    out[poff + 1] = (float)me;
    out[poff + 2] = (float)mu;
  }
}

extern "C" void kernel_launch(void* const* d_in, const int* in_sizes, int n_in,
                              void* d_out, int out_size, void* d_ws, size_t ws_size,
                              hipStream_t stream) {
  const float* z = (const float*)d_in[0];
  const int* bid = (const int*)d_in[1];
  const float* cb = (const float*)d_in[2];
  int N = in_sizes[1];
  int Dd = in_sizes[0] / N;
  int K = in_sizes[2] / Dd;
  float* out = (float*)d_out;

  // workspace layout (256B-aligned chunks)
  char* ws = (char*)d_ws;
  size_t off = 0;
  auto alloc = [&](size_t bytes) {
    void* p = ws + off;
    off += (bytes + 255) & ~(size_t)255;
    return p;
  };
  unsigned int* counts = (unsigned int*)alloc((size_t)NBATCH * K * 4);
  double* sse  = (double*)alloc(8);
  double* perp = (double*)alloc(8 * NBATCH);
  double* ent  = (double*)alloc(8 * NBATCH);
  double* uniq = (double*)alloc(8 * NBATCH);
  float* csq = (float*)alloc((size_t)K * 4);
  short* cbh = (short*)alloc((size_t)K * D64 * 2);
  unsigned* pmin = (unsigned*)alloc((size_t)N * 4);
  unsigned int* pcnt = (unsigned int*)alloc((size_t)N * 4);
  int* cand = (int*)alloc((size_t)N * NSLOT * 4);
  int* fidx = (int*)alloc((size_t)N * 4);

  (void)hipMemsetAsync(counts, 0, (size_t)NBATCH * K * 4, stream);
  (void)hipMemsetAsync(sse, 0, 8, stream);
  (void)hipMemsetAsync(pcnt, 0, (size_t)N * 4, stream);
  (void)hipMemsetAsync(pmin, 0xFF, (size_t)N * 4, stream);   // +inf packed

  size_t ioff = (size_t)N * Dd + 2;

  csq_cvt_kernel<<<(K * 64 + 255) / 256, 256, 0, stream>>>(cb, csq, cbh, K);
  dim3 fg(N / 128, KSPL);
  filter_min_kernel<<<fg, 256, 0, stream>>>(z, cbh, csq, pmin, N, K);
  emit_kernel<<<fg, 256, 0, stream>>>(z, cbh, csq, pmin, pcnt, cand, N, K);
  rescore_assign_kernel<<<(N + 255) / 256, 256, 0, stream>>>(
      z, cb, csq, pcnt, cand, bid, fidx, out + ioff, counts, N, K);
  quant_kernel<<<(N * 16 + 255) / 256, 256, 0, stream>>>(z, cb, fidx, out, sse, N);
  stats_kernel<<<NBATCH, 256, 0, stream>>>(counts, perp, ent, uniq, K);
  final_kernel<<<1, 64, 0, stream>>>(sse, perp, ent, uniq, out, N);
}

// Round 7
// 352.388 us; speedup vs baseline: 5.9337x; 1.8104x over previous
//
#include <hip/hip_runtime.h>
#include <math.h>

#define D64 64
#define NBATCH 8
#define CBAND 2.0f
#define NSLOT 16
#define CHUNK 128                 // codes per LDS chunk (16 KB)

typedef short s16x8 __attribute__((ext_vector_type(8)));   // 8 bf16 (bit pattern)
typedef float f32x4 __attribute__((ext_vector_type(4)));

#define GLOAD16(g, l) __builtin_amdgcn_global_load_lds( \
    (const __attribute__((address_space(1))) unsigned*)(g), \
    (__attribute__((address_space(3))) unsigned*)(l), 16, 0, 0)
#define GLOAD4(g, l) __builtin_amdgcn_global_load_lds( \
    (const __attribute__((address_space(1))) unsigned*)(g), \
    (__attribute__((address_space(3))) unsigned*)(l), 4, 0, 0)

__device__ inline short f2bf(float f) {
  unsigned u = __builtin_bit_cast(unsigned, f);
  unsigned r = (u + 0x7FFFu + ((u >> 16) & 1u)) >> 16;
  return (short)r;
}

// ---------------- c_sq + bf16 convert ----------------
__global__ __launch_bounds__(256) void csq_cvt_kernel(
    const float* __restrict__ cb, float* __restrict__ csq,
    short* __restrict__ cbh, int K) {
  int t = blockIdx.x * blockDim.x + threadIdx.x;
  int row = t >> 6, lane = t & 63;
  if (row >= K) return;
  float v = cb[(size_t)row * D64 + lane];
  cbh[(size_t)row * D64 + lane] = f2bf(v);
  v *= v;
  #pragma unroll
  for (int off = 32; off; off >>= 1) v += __shfl_xor(v, off, 64);
  if (lane == 0) csq[row] = v;
}

// ---------------- fused filter: sweep A (min) + sweep B (emit) ----------------
// block = 4 waves x 32 points = 128 points, full K, LDS-staged codebook.
// LDS layout swizzle: byte X stored at X ^ (((X>>7)&7)<<4) relative (involution).
__global__ __launch_bounds__(256, 2) void fused_filter_kernel(
    const float* __restrict__ z, const short* __restrict__ cbh,
    const float* __restrict__ csq,
    unsigned int* __restrict__ pcnt, int* __restrict__ cand, int N, int K) {
  __shared__ short lcb[2][CHUNK * D64];     // 2 x 16 KB
  __shared__ float lcsq[2][CHUNK];          // 2 x 512 B

  int w = threadIdx.x >> 6;
  int l = threadIdx.x & 63;
  int lr = l & 15, lg = l >> 4;
  int base = blockIdx.x * 128 + w * 32;
  int nchunk = K / CHUNK;                   // 64

  // ---- A fragments (z rows) ----
  s16x8 A[2][2];
  #pragma unroll
  for (int rt = 0; rt < 2; ++rt) {
    int row = base + rt * 16 + lr;
    #pragma unroll
    for (int kh = 0; kh < 2; ++kh) {
      const float4* zp = reinterpret_cast<const float4*>(
          z + (size_t)row * D64 + kh * 32 + lg * 8);
      float4 p0 = zp[0], p1 = zp[1];
      s16x8 t;
      t[0] = f2bf(p0.x); t[1] = f2bf(p0.y); t[2] = f2bf(p0.z); t[3] = f2bf(p0.w);
      t[4] = f2bf(p1.x); t[5] = f2bf(p1.y); t[6] = f2bf(p1.z); t[7] = f2bf(p1.w);
      A[rt][kh] = t;
    }
  }

  // per-lane swizzled LDS read offsets (constant over inner iters; inner
  // iter adds i*2048 which only touches bits >= 11)
  int sw = (lr & 7) << 4;
  int p0off = ((lr * 128 + lg * 16) ^ sw);
  int p1off = ((lr * 128 + 64 + lg * 16) ^ sw);
  int swl = (l >> 3) << 4;                  // staging source swizzle

  // ---- staging helper (macro to keep literal size args) ----
  const char* cbbytes = (const char*)cbh;
#define STAGE(chunk, b)                                                       \
  {                                                                           \
    const char* src = cbbytes + (size_t)(chunk) * (CHUNK * 128);              \
    char* dstb = (char*)lcb[b];                                               \
    _Pragma("unroll")                                                         \
    for (int j = 0; j < 4; ++j) {                                             \
      int X = (w * 4 + j) * 1024 + l * 16;                                    \
      GLOAD16(src + (X ^ swl), dstb + (w * 4 + j) * 1024);                    \
    }                                                                         \
    if (w < 2) {                                                              \
      const char* csrc = (const char*)(csq + (chunk) * CHUNK) + w * 256;      \
      GLOAD4(csrc + l * 4, (char*)lcsq[b] + w * 256);                         \
    }                                                                         \
  }

  // ================= sweep A: per-point min =================
  float rmin[2][4];
  #pragma unroll
  for (int rt = 0; rt < 2; ++rt)
    #pragma unroll
    for (int r = 0; r < 4; ++r) rmin[rt][r] = INFINITY;

  STAGE(0, 0);
  __syncthreads();
  for (int c = 0; c < nchunk; ++c) {
    int b = c & 1;
    if (c + 1 < nchunk) STAGE(c + 1, b ^ 1);
    const char* pb0 = (const char*)lcb[b] + p0off;
    const char* pb1 = (const char*)lcb[b] + p1off;
    const float* cqb = lcsq[b] + lr;
    #pragma unroll
    for (int i = 0; i < 8; ++i) {
      s16x8 B0 = *(const s16x8*)(pb0 + i * 2048);
      s16x8 B1 = *(const s16x8*)(pb1 + i * 2048);
      float cq = cqb[i * 16];
      #pragma unroll
      for (int rt = 0; rt < 2; ++rt) {
        f32x4 acc = {0.f, 0.f, 0.f, 0.f};
        acc = __builtin_amdgcn_mfma_f32_16x16x32_bf16(A[rt][0], B0, acc, 0, 0, 0);
        acc = __builtin_amdgcn_mfma_f32_16x16x32_bf16(A[rt][1], B1, acc, 0, 0, 0);
        #pragma unroll
        for (int r = 0; r < 4; ++r) {
          float s = fmaf(-2.0f, acc[r], cq);
          rmin[rt][r] = fminf(rmin[rt][r], s);
        }
      }
    }
    __syncthreads();
  }

  // reduce over the 16 code-cols (lane bits 0..3) -> per-point threshold
  float thr[2][4];
  #pragma unroll
  for (int rt = 0; rt < 2; ++rt)
    #pragma unroll
    for (int r = 0; r < 4; ++r) {
      float v = rmin[rt][r];
      v = fminf(v, __shfl_xor(v, 1, 64));
      v = fminf(v, __shfl_xor(v, 2, 64));
      v = fminf(v, __shfl_xor(v, 4, 64));
      v = fminf(v, __shfl_xor(v, 8, 64));
      thr[rt][r] = v + CBAND;
    }

  // ================= sweep B: emit candidates =================
  STAGE(0, 0);
  __syncthreads();
  for (int c = 0; c < nchunk; ++c) {
    int b = c & 1;
    if (c + 1 < nchunk) STAGE(c + 1, b ^ 1);
    const char* pb0 = (const char*)lcb[b] + p0off;
    const char* pb1 = (const char*)lcb[b] + p1off;
    const float* cqb = lcsq[b] + lr;
    #pragma unroll
    for (int i = 0; i < 8; ++i) {
      s16x8 B0 = *(const s16x8*)(pb0 + i * 2048);
      s16x8 B1 = *(const s16x8*)(pb1 + i * 2048);
      float cq = cqb[i * 16];
      float s[2][4];
      #pragma unroll
      for (int rt = 0; rt < 2; ++rt) {
        f32x4 acc = {0.f, 0.f, 0.f, 0.f};
        acc = __builtin_amdgcn_mfma_f32_16x16x32_bf16(A[rt][0], B0, acc, 0, 0, 0);
        acc = __builtin_amdgcn_mfma_f32_16x16x32_bf16(A[rt][1], B1, acc, 0, 0, 0);
        #pragma unroll
        for (int r = 0; r < 4; ++r)
          s[rt][r] = fmaf(-2.0f, acc[r], cq);
      }
      int hits = 0;
      #pragma unroll
      for (int rt = 0; rt < 2; ++rt)
        #pragma unroll
        for (int r = 0; r < 4; ++r)
          hits |= (s[rt][r] <= thr[rt][r]) ? (1 << (rt * 4 + r)) : 0;
      if (__any(hits != 0)) {
        int k = c * CHUNK + i * 16 + lr;
        #pragma unroll
        for (int rt = 0; rt < 2; ++rt)
          #pragma unroll
          for (int r = 0; r < 4; ++r) {
            if (hits & (1 << (rt * 4 + r))) {
              int n = base + rt * 16 + lg * 4 + r;
              unsigned slot = atomicAdd(&pcnt[n], 1u);
              if (slot < NSLOT) cand[(size_t)n * NSLOT + slot] = k;
            }
          }
      }
    }
    __syncthreads();
  }
#undef STAGE
}

// ---------------- exact fp32 rescore of candidates + fp64 tiebreak ----------------
__global__ __launch_bounds__(256) void rescore_assign_kernel(
    const float* __restrict__ z, const float* __restrict__ cb,
    const float* __restrict__ csq,
    const unsigned int* __restrict__ pcnt, const int* __restrict__ cand,
    const int* __restrict__ batch_raw,
    int* __restrict__ fidx, float* __restrict__ out_idx,
    unsigned int* __restrict__ counts, int N, int K) {
  int n = blockIdx.x * blockDim.x + threadIdx.x;
  if (n >= N) return;
  int cnt = min(pcnt[n], (unsigned)NSLOT);

  const float4* z4 = reinterpret_cast<const float4*>(z) + (size_t)n * 16;
  float4 zr[16];
  #pragma unroll
  for (int d = 0; d < 16; ++d) zr[d] = z4[d];

  float b1 = INFINITY, b2 = INFINITY;
  int i1 = 0x7FFFFFFF, i2 = 0x7FFFFFFF;
  for (int c = 0; c < cnt; ++c) {
    int k = cand[(size_t)n * NSLOT + c];
    const float4* cr = reinterpret_cast<const float4*>(cb) + (size_t)k * 16;
    float4 a = {0.f, 0.f, 0.f, 0.f};
    #pragma unroll
    for (int d = 0; d < 16; ++d) {
      float4 q = cr[d], zz = zr[d];
      a.x = fmaf(q.x, zz.x, a.x);
      a.y = fmaf(q.y, zz.y, a.y);
      a.z = fmaf(q.z, zz.z, a.z);
      a.w = fmaf(q.w, zz.w, a.w);
    }
    float s = csq[k] - 2.0f * ((a.x + a.y) + (a.z + a.w));
    // top-2 with (score, index) ordering (candidates arrive unordered)
    bool bet1 = (s < b1) || (s == b1 && k < i1);
    float cs = bet1 ? b1 : s;  int ci = bet1 ? i1 : k;
    b1 = bet1 ? s : b1;        i1 = bet1 ? k : i1;
    bool bet2 = (cs < b2) || (cs == b2 && ci < i2);
    b2 = bet2 ? cs : b2;       i2 = bet2 ? ci : i2;
  }

  int final_i = i1;
  if (cnt >= 2 && (b2 - b1) < 1e-3f) {
    const float* zp  = z  + (size_t)n  * D64;
    const float* c1p = cb + (size_t)i1 * D64;
    const float* c2p = cb + (size_t)i2 * D64;
    double d0 = 0.0, d1 = 0.0;
    for (int d = 0; d < D64; ++d) {
      double t0 = (double)zp[d] - (double)c1p[d];
      double t1 = (double)zp[d] - (double)c2p[d];
      d0 += t0 * t0;
      d1 += t1 * t1;
    }
    if (d1 < d0 || (d1 == d0 && i2 < i1)) final_i = i2;
  }

  fidx[n] = final_i;
  out_idx[n] = (float)final_i;

  int is64 = (batch_raw[N - 1] == 0) ? 1 : 0;
  int b = is64 ? batch_raw[2 * n] : batch_raw[n];
  atomicAdd(&counts[(size_t)b * K + final_i], 1u);
}

// ---------------- gather + straight-through + SSE ----------------
__global__ __launch_bounds__(256) void quant_kernel(
    const float* __restrict__ z, const float* __restrict__ cb,
    const int* __restrict__ fidx, float* __restrict__ outq,
    double* __restrict__ sse, int N) {
  __shared__ double red[4];
  int g = blockIdx.x * blockDim.x + threadIdx.x;
  int total4 = N * 16;
  double local = 0.0;
  if (g < total4) {
    int n = g >> 4, d4 = g & 15;
    int k = fidx[n];
    float4 zz = reinterpret_cast<const float4*>(z)[g];
    float4 qq = reinterpret_cast<const float4*>(cb)[(size_t)k * 16 + d4];
    float4 t = {qq.x - zz.x, qq.y - zz.y, qq.z - zz.z, qq.w - zz.w};
    float4 st = {zz.x + t.x, zz.y + t.y, zz.z + t.z, zz.w + t.w};
    reinterpret_cast<float4*>(outq)[g] = st;
    local = (double)t.x * t.x + (double)t.y * t.y +
            (double)t.z * t.z + (double)t.w * t.w;
  }
  #pragma unroll
  for (int off = 32; off; off >>= 1) local += __shfl_xor(local, off, 64);
  int lane = threadIdx.x & 63, w = threadIdx.x >> 6;
  if (lane == 0) red[w] = local;
  __syncthreads();
  if (threadIdx.x == 0) atomicAdd(sse, red[0] + red[1] + red[2] + red[3]);
}

// ---------------- per-batch entropy / perplexity / unique ----------------
__global__ __launch_bounds__(256) void stats_kernel(
    const unsigned int* __restrict__ counts,
    double* __restrict__ perp, double* __restrict__ ent,
    double* __restrict__ uniq, int K) {
  __shared__ double sh4[4], she[4], shu[4];
  int b = blockIdx.x;
  const unsigned int* c = counts + (size_t)b * K;
  int lane = threadIdx.x & 63, w = threadIdx.x >> 6;

  double tot = 0.0;
  for (int k = threadIdx.x; k < K; k += blockDim.x) tot += (double)c[k];
  #pragma unroll
  for (int off = 32; off; off >>= 1) tot += __shfl_xor(tot, off, 64);
  if (lane == 0) sh4[w] = tot;
  __syncthreads();
  double total = sh4[0] + sh4[1] + sh4[2] + sh4[3];
  double denom = fmax(total, 1.0);

  double e = 0.0, u = 0.0;
  for (int k = threadIdx.x; k < K; k += blockDim.x) {
    double cc = (double)c[k];
    double p = cc / denom;
    e -= p * log(p + 1e-10);
    if (cc > 0.0) u += 1.0;
  }
  #pragma unroll
  for (int off = 32; off; off >>= 1) {
    e += __shfl_xor(e, off, 64);
    u += __shfl_xor(u, off, 64);
  }
  if (lane == 0) { she[w] = e; shu[w] = u; }
  __syncthreads();
  if (threadIdx.x == 0) {
    double E = she[0] + she[1] + she[2] + she[3];
    double U = shu[0] + shu[1] + shu[2] + shu[3];
    ent[b] = E; perp[b] = exp(E); uniq[b] = U;
  }
}

// ---------------- finalize scalars ----------------
__global__ void final_kernel(const double* __restrict__ sse,
                             const double* __restrict__ perp,
                             const double* __restrict__ ent,
                             const double* __restrict__ uniq,
                             float* __restrict__ out, int N) {
  if (threadIdx.x == 0 && blockIdx.x == 0) {
    double mp = 0.0, me = 0.0, mu = 0.0;
    for (int b = 0; b < NBATCH; ++b) { mp += perp[b]; me += ent[b]; mu += uniq[b]; }
    mp /= NBATCH; me /= NBATCH; mu /= NBATCH;
    double loss = *sse / ((double)N * (double)D64);
    size_t voff = (size_t)N * D64;
    size_t coff = voff + 1;
    size_t poff = coff + 1 + (size_t)N;
    out[voff] = (float)loss;
    out[coff] = (float)loss;
    out[poff] = (float)mp;
    out[poff + 1] = (float)me;
    out[poff + 2] = (float)mu;
  }
}

extern "C" void kernel_launch(void* const* d_in, const int* in_sizes, int n_in,
                              void* d_out, int out_size, void* d_ws, size_t ws_size,
                              hipStream_t stream) {
  const float* z = (const float*)d_in[0];
  const int* bid = (const int*)d_in[1];
  const float* cb = (const float*)d_in[2];
  int N = in_sizes[1];
  int Dd = in_sizes[0] / N;
  int K = in_sizes[2] / Dd;
  float* out = (float*)d_out;

  // workspace layout (256B-aligned chunks)
  char* ws = (char*)d_ws;
  size_t off = 0;
  auto alloc = [&](size_t bytes) {
    void* p = ws + off;
    off += (bytes + 255) & ~(size_t)255;
    return p;
  };
  unsigned int* counts = (unsigned int*)alloc((size_t)NBATCH * K * 4);
  double* sse  = (double*)alloc(8);
  double* perp = (double*)alloc(8 * NBATCH);
  double* ent  = (double*)alloc(8 * NBATCH);
  double* uniq = (double*)alloc(8 * NBATCH);
  float* csq = (float*)alloc((size_t)K * 4);
  short* cbh = (short*)alloc((size_t)K * D64 * 2);
  unsigned int* pcnt = (unsigned int*)alloc((size_t)N * 4);
  int* cand = (int*)alloc((size_t)N * NSLOT * 4);
  int* fidx = (int*)alloc((size_t)N * 4);

  (void)hipMemsetAsync(counts, 0, (size_t)NBATCH * K * 4, stream);
  (void)hipMemsetAsync(sse, 0, 8, stream);
  (void)hipMemsetAsync(pcnt, 0, (size_t)N * 4, stream);

  size_t ioff = (size_t)N * Dd + 2;

  csq_cvt_kernel<<<(K * 64 + 255) / 256, 256, 0, stream>>>(cb, csq, cbh, K);
  fused_filter_kernel<<<N / 128, 256, 0, stream>>>(z, cbh, csq, pcnt, cand, N, K);
  rescore_assign_kernel<<<(N + 255) / 256, 256, 0, stream>>>(
      z, cb, csq, pcnt, cand, bid, fidx, out + ioff, counts, N, K);
  quant_kernel<<<(N * 16 + 255) / 256, 256, 0, stream>>>(z, cb, fidx, out, sse, N);
  stats_kernel<<<NBATCH, 256, 0, stream>>>(counts, perp, ent, uniq, K);
  final_kernel<<<1, 64, 0, stream>>>(sse, perp, ent, uniq, out, N);
}

// Round 8
// 290.061 us; speedup vs baseline: 7.2087x; 1.2149x over previous
//
#include <hip/hip_runtime.h>
#include <math.h>

#define D64 64
#define NBATCH 8
#define CBAND 2.0f
#define NSLOT 16
#define CHUNK 128                 // codes per LDS chunk (16 KB)
#define NCHUNK 64                 // K / CHUNK
#define NV (2 * NCHUNK)           // virtual chunks: sweep A then sweep B

typedef short s16x8 __attribute__((ext_vector_type(8)));   // 8 bf16 (bit pattern)
typedef float f32x4 __attribute__((ext_vector_type(4)));

#define GLOAD16(g, l) __builtin_amdgcn_global_load_lds( \
    (const __attribute__((address_space(1))) unsigned*)(g), \
    (__attribute__((address_space(3))) unsigned*)(l), 16, 0, 0)
#define GLOAD4(g, l) __builtin_amdgcn_global_load_lds( \
    (const __attribute__((address_space(1))) unsigned*)(g), \
    (__attribute__((address_space(3))) unsigned*)(l), 4, 0, 0)

__device__ inline short f2bf(float f) {
  unsigned u = __builtin_bit_cast(unsigned, f);
  unsigned r = (u + 0x7FFFu + ((u >> 16) & 1u)) >> 16;
  return (short)r;
}

// ---------------- c_sq + bf16 convert + workspace zeroing ----------------
__global__ __launch_bounds__(256) void csq_cvt_kernel(
    const float* __restrict__ cb, float* __restrict__ csq,
    short* __restrict__ cbh,
    unsigned int* __restrict__ counts, unsigned int* __restrict__ pcnt,
    double* __restrict__ sse, int K, int Npts) {
  int t = blockIdx.x * blockDim.x + threadIdx.x;
  // fold former memsets into this kernel (one pass, deterministic)
  if (t < NBATCH * K) counts[t] = 0u;
  if (t < Npts) pcnt[t] = 0u;
  if (t == 0) *sse = 0.0;
  int row = t >> 6, lane = t & 63;
  if (row >= K) return;
  float v = cb[(size_t)row * D64 + lane];
  cbh[(size_t)row * D64 + lane] = f2bf(v);
  v *= v;
  #pragma unroll
  for (int off = 32; off; off >>= 1) v += __shfl_xor(v, off, 64);
  if (lane == 0) csq[row] = v;
}

// ---------------- fused filter: sweep A (min) + sweep B (emit) ----------------
// block = 4 waves x 32 points = 128 points, full K, LDS-staged codebook.
// 3-deep buffers + counted vmcnt (never 0 in steady state) + raw barriers.
// Every wave issues exactly 5 staging loads per chunk (uniform vmcnt).
__global__ __launch_bounds__(256, 2) void fused_filter_kernel(
    const float* __restrict__ z, const short* __restrict__ cbh,
    const float* __restrict__ csq,
    unsigned int* __restrict__ pcnt, int* __restrict__ cand, int N, int K) {
  __shared__ short lcb[3][CHUNK * D64];     // 3 x 16 KB
  __shared__ float lcsq[3][CHUNK];          // 3 x 512 B

  int w = threadIdx.x >> 6;
  int l = threadIdx.x & 63;
  int lr = l & 15, lg = l >> 4;
  int base = blockIdx.x * 128 + w * 32;

  // ---- A fragments (z rows) ----
  s16x8 A[2][2];
  #pragma unroll
  for (int rt = 0; rt < 2; ++rt) {
    int row = base + rt * 16 + lr;
    #pragma unroll
    for (int kh = 0; kh < 2; ++kh) {
      const float4* zp = reinterpret_cast<const float4*>(
          z + (size_t)row * D64 + kh * 32 + lg * 8);
      float4 p0 = zp[0], p1 = zp[1];
      s16x8 t;
      t[0] = f2bf(p0.x); t[1] = f2bf(p0.y); t[2] = f2bf(p0.z); t[3] = f2bf(p0.w);
      t[4] = f2bf(p1.x); t[5] = f2bf(p1.y); t[6] = f2bf(p1.z); t[7] = f2bf(p1.w);
      A[rt][kh] = t;
    }
  }

  // per-lane swizzled LDS read offsets (constant over inner iters)
  int sw = (lr & 7) << 4;
  int p0off = ((lr * 128 + lg * 16) ^ sw);
  int p1off = ((lr * 128 + 64 + lg * 16) ^ sw);
  int swl = (l >> 3) << 4;                  // staging source swizzle

  const char* cbbytes = (const char*)cbh;
  // STAGE: 4x GLOAD16 (cbh chunk, pre-swizzled source) + 1x GLOAD4 (csq).
  // waves 2,3 duplicate waves 0,1's csq load (same src+dst) for uniform count.
#define STAGE(chunk, b)                                                       \
  {                                                                           \
    const char* src = cbbytes + (size_t)(chunk) * (CHUNK * 128);              \
    char* dstb = (char*)lcb[b];                                               \
    _Pragma("unroll")                                                         \
    for (int j = 0; j < 4; ++j) {                                             \
      int X = (w * 4 + j) * 1024 + l * 16;                                    \
      GLOAD16(src + (X ^ swl), dstb + (w * 4 + j) * 1024);                    \
    }                                                                         \
    const char* csrc = (const char*)(csq + (chunk) * CHUNK) + (w & 1) * 256;  \
    GLOAD4(csrc + l * 4, (char*)lcsq[b] + (w & 1) * 256);                     \
  }

  float rmin[2][4];
  #pragma unroll
  for (int rt = 0; rt < 2; ++rt)
    #pragma unroll
    for (int r = 0; r < 4; ++r) rmin[rt][r] = INFINITY;
  float thr[2][4];

  // compute one virtual chunk out of buffer b
  auto do_chunk = [&](int v, int b) {
    const char* pb0 = (const char*)lcb[b] + p0off;
    const char* pb1 = (const char*)lcb[b] + p1off;
    const float* cqb = lcsq[b] + lr;
    if (v < NCHUNK) {
      // ---- sweep A: accumulate per-point min ----
      #pragma unroll
      for (int i = 0; i < 8; ++i) {
        s16x8 B0 = *(const s16x8*)(pb0 + i * 2048);
        s16x8 B1 = *(const s16x8*)(pb1 + i * 2048);
        float cq = cqb[i * 16];
        #pragma unroll
        for (int rt = 0; rt < 2; ++rt) {
          f32x4 acc = {0.f, 0.f, 0.f, 0.f};
          acc = __builtin_amdgcn_mfma_f32_16x16x32_bf16(A[rt][0], B0, acc, 0, 0, 0);
          acc = __builtin_amdgcn_mfma_f32_16x16x32_bf16(A[rt][1], B1, acc, 0, 0, 0);
          #pragma unroll
          for (int r = 0; r < 4; ++r) {
            float s = fmaf(-2.0f, acc[r], cq);
            rmin[rt][r] = fminf(rmin[rt][r], s);
          }
        }
      }
      if (v == NCHUNK - 1) {
        // reduce over the 16 code-cols (lane bits 0..3) -> per-point threshold
        #pragma unroll
        for (int rt = 0; rt < 2; ++rt)
          #pragma unroll
          for (int r = 0; r < 4; ++r) {
            float x = rmin[rt][r];
            x = fminf(x, __shfl_xor(x, 1, 64));
            x = fminf(x, __shfl_xor(x, 2, 64));
            x = fminf(x, __shfl_xor(x, 4, 64));
            x = fminf(x, __shfl_xor(x, 8, 64));
            thr[rt][r] = x + CBAND;
          }
      }
    } else {
      // ---- sweep B: emit candidates within band ----
      int c = v - NCHUNK;
      #pragma unroll
      for (int i = 0; i < 8; ++i) {
        s16x8 B0 = *(const s16x8*)(pb0 + i * 2048);
        s16x8 B1 = *(const s16x8*)(pb1 + i * 2048);
        float cq = cqb[i * 16];
        float s[2][4];
        #pragma unroll
        for (int rt = 0; rt < 2; ++rt) {
          f32x4 acc = {0.f, 0.f, 0.f, 0.f};
          acc = __builtin_amdgcn_mfma_f32_16x16x32_bf16(A[rt][0], B0, acc, 0, 0, 0);
          acc = __builtin_amdgcn_mfma_f32_16x16x32_bf16(A[rt][1], B1, acc, 0, 0, 0);
          #pragma unroll
          for (int r = 0; r < 4; ++r)
            s[rt][r] = fmaf(-2.0f, acc[r], cq);
        }
        int hits = 0;
        #pragma unroll
        for (int rt = 0; rt < 2; ++rt)
          #pragma unroll
          for (int r = 0; r < 4; ++r)
            hits |= (s[rt][r] <= thr[rt][r]) ? (1 << (rt * 4 + r)) : 0;
        if (__any(hits != 0)) {
          int k = c * CHUNK + i * 16 + lr;
          #pragma unroll
          for (int rt = 0; rt < 2; ++rt)
            #pragma unroll
            for (int r = 0; r < 4; ++r) {
              if (hits & (1 << (rt * 4 + r))) {
                int n = base + rt * 16 + lg * 4 + r;
                unsigned slot = atomicAdd(&pcnt[n], 1u);
                if (slot < NSLOT) cand[(size_t)n * NSLOT + slot] = k;
              }
            }
        }
      }
    }
  };

  // prologue: fill the 3 buffers (vchunks 0,1,2)
  STAGE(0, 0);
  STAGE(1, 1);
  STAGE(2, 2);

  // main loop: vchunks 0..NV-4, staging v+3 each iter.
  // wait vmcnt(10): chunk v's 5 loads done, chunks v+1,v+2 (10) stay in flight.
  for (int v = 0; v < NV - 3; ++v) {
    asm volatile("s_waitcnt vmcnt(10)" ::: "memory");
    __builtin_amdgcn_sched_barrier(0);
    __builtin_amdgcn_s_barrier();
    do_chunk(v, v % 3);
    asm volatile("s_waitcnt lgkmcnt(0)" ::: "memory");
    __builtin_amdgcn_sched_barrier(0);
    __builtin_amdgcn_s_barrier();
    STAGE((v + 3) & (NCHUNK - 1), v % 3);   // vchunk v+3 -> data chunk (v+3)%64
  }
  // epilogue: v = NV-3 (2 chunks in flight), NV-2 (1), NV-1 (0)
  {
    int v = NV - 3;
    asm volatile("s_waitcnt vmcnt(10)" ::: "memory");
    __builtin_amdgcn_sched_barrier(0);
    __builtin_amdgcn_s_barrier();
    do_chunk(v, v % 3);
    asm volatile("s_waitcnt lgkmcnt(0)" ::: "memory");
    __builtin_amdgcn_s_barrier();
  }
  {
    int v = NV - 2;
    asm volatile("s_waitcnt vmcnt(5)" ::: "memory");
    __builtin_amdgcn_sched_barrier(0);
    __builtin_amdgcn_s_barrier();
    do_chunk(v, v % 3);
    asm volatile("s_waitcnt lgkmcnt(0)" ::: "memory");
    __builtin_amdgcn_s_barrier();
  }
  {
    int v = NV - 1;
    asm volatile("s_waitcnt vmcnt(0)" ::: "memory");
    __builtin_amdgcn_sched_barrier(0);
    __builtin_amdgcn_s_barrier();
    do_chunk(v, v % 3);
  }
#undef STAGE
}

// ---- exact fp32 rescore + fp64 tiebreak + counts + index out + quantize ----
__global__ __launch_bounds__(256) void rescore_quant_kernel(
    const float* __restrict__ z, const float* __restrict__ cb,
    const float* __restrict__ csq,
    const unsigned int* __restrict__ pcnt, const int* __restrict__ cand,
    const int* __restrict__ batch_raw,
    float* __restrict__ out_idx, float* __restrict__ outq,
    unsigned int* __restrict__ counts, double* __restrict__ sse,
    int N, int K) {
  __shared__ double red[4];
  int n = blockIdx.x * blockDim.x + threadIdx.x;
  int cnt = min(pcnt[n], (unsigned)NSLOT);

  const float4* z4 = reinterpret_cast<const float4*>(z) + (size_t)n * 16;
  float4 zr[16];
  #pragma unroll
  for (int d = 0; d < 16; ++d) zr[d] = z4[d];

  float b1 = INFINITY, b2 = INFINITY;
  int i1 = 0x7FFFFFFF, i2 = 0x7FFFFFFF;
  for (int c = 0; c < cnt; ++c) {
    int k = cand[(size_t)n * NSLOT + c];
    const float4* cr = reinterpret_cast<const float4*>(cb) + (size_t)k * 16;
    float4 a = {0.f, 0.f, 0.f, 0.f};
    #pragma unroll
    for (int d = 0; d < 16; ++d) {
      float4 q = cr[d], zz = zr[d];
      a.x = fmaf(q.x, zz.x, a.x);
      a.y = fmaf(q.y, zz.y, a.y);
      a.z = fmaf(q.z, zz.z, a.z);
      a.w = fmaf(q.w, zz.w, a.w);
    }
    float s = csq[k] - 2.0f * ((a.x + a.y) + (a.z + a.w));
    // top-2 with (score, index) ordering (candidates arrive unordered)
    bool bet1 = (s < b1) || (s == b1 && k < i1);
    float cs = bet1 ? b1 : s;  int ci = bet1 ? i1 : k;
    b1 = bet1 ? s : b1;        i1 = bet1 ? k : i1;
    bool bet2 = (cs < b2) || (cs == b2 && ci < i2);
    b2 = bet2 ? cs : b2;       i2 = bet2 ? ci : i2;
  }

  int final_i = i1;
  if (cnt >= 2 && (b2 - b1) < 1e-3f) {
    const float* zp  = z  + (size_t)n  * D64;
    const float* c1p = cb + (size_t)i1 * D64;
    const float* c2p = cb + (size_t)i2 * D64;
    double d0 = 0.0, d1 = 0.0;
    for (int d = 0; d < D64; ++d) {
      double t0 = (double)zp[d] - (double)c1p[d];
      double t1 = (double)zp[d] - (double)c2p[d];
      d0 += t0 * t0;
      d1 += t1 * t1;
    }
    if (d1 < d0 || (d1 == d0 && i2 < i1)) final_i = i2;
  }

  out_idx[n] = (float)final_i;

  int is64 = (batch_raw[N - 1] == 0) ? 1 : 0;
  int b = is64 ? batch_raw[2 * n] : batch_raw[n];
  atomicAdd(&counts[(size_t)b * K + final_i], 1u);

  // ---- quantize + straight-through + SSE (z row already in registers) ----
  const float4* cr = reinterpret_cast<const float4*>(cb) + (size_t)final_i * 16;
  float4* oq = reinterpret_cast<float4*>(outq) + (size_t)n * 16;
  double local = 0.0;
  #pragma unroll
  for (int d = 0; d < 16; ++d) {
    float4 q = cr[d], zz = zr[d];
    float4 t = {q.x - zz.x, q.y - zz.y, q.z - zz.z, q.w - zz.w};
    float4 st = {zz.x + t.x, zz.y + t.y, zz.z + t.z, zz.w + t.w};
    oq[d] = st;
    local += (double)t.x * t.x + (double)t.y * t.y +
             (double)t.z * t.z + (double)t.w * t.w;
  }
  #pragma unroll
  for (int off = 32; off; off >>= 1) local += __shfl_xor(local, off, 64);
  int lane = threadIdx.x & 63, wv = threadIdx.x >> 6;
  if (lane == 0) red[wv] = local;
  __syncthreads();
  if (threadIdx.x == 0) atomicAdd(sse, red[0] + red[1] + red[2] + red[3]);
}

// ---------------- per-batch entropy / perplexity / unique ----------------
__global__ __launch_bounds__(256) void stats_kernel(
    const unsigned int* __restrict__ counts,
    double* __restrict__ perp, double* __restrict__ ent,
    double* __restrict__ uniq, int K) {
  __shared__ double sh4[4], she[4], shu[4];
  int b = blockIdx.x;
  const unsigned int* c = counts + (size_t)b * K;
  int lane = threadIdx.x & 63, w = threadIdx.x >> 6;

  double tot = 0.0;
  for (int k = threadIdx.x; k < K; k += blockDim.x) tot += (double)c[k];
  #pragma unroll
  for (int off = 32; off; off >>= 1) tot += __shfl_xor(tot, off, 64);
  if (lane == 0) sh4[w] = tot;
  __syncthreads();
  double total = sh4[0] + sh4[1] + sh4[2] + sh4[3];
  double denom = fmax(total, 1.0);

  double e = 0.0, u = 0.0;
  for (int k = threadIdx.x; k < K; k += blockDim.x) {
    double cc = (double)c[k];
    double p = cc / denom;
    e -= p * log(p + 1e-10);
    if (cc > 0.0) u += 1.0;
  }
  #pragma unroll
  for (int off = 32; off; off >>= 1) {
    e += __shfl_xor(e, off, 64);
    u += __shfl_xor(u, off, 64);
  }
  if (lane == 0) { she[w] = e; shu[w] = u; }
  __syncthreads();
  if (threadIdx.x == 0) {
    double E = she[0] + she[1] + she[2] + she[3];
    double U = shu[0] + shu[1] + shu[2] + shu[3];
    ent[b] = E; perp[b] = exp(E); uniq[b] = U;
  }
}

// ---------------- finalize scalars ----------------
__global__ void final_kernel(const double* __restrict__ sse,
                             const double* __restrict__ perp,
                             const double* __restrict__ ent,
                             const double* __restrict__ uniq,
                             float* __restrict__ out, int N) {
  if (threadIdx.x == 0 && blockIdx.x == 0) {
    double mp = 0.0, me = 0.0, mu = 0.0;
    for (int b = 0; b < NBATCH; ++b) { mp += perp[b]; me += ent[b]; mu += uniq[b]; }
    mp /= NBATCH; me /= NBATCH; mu /= NBATCH;
    double loss = *sse / ((double)N * (double)D64);
    size_t voff = (size_t)N * D64;
    size_t coff = voff + 1;
    size_t poff = coff + 1 + (size_t)N;
    out[voff] = (float)loss;
    out[coff] = (float)loss;
    out[poff] = (float)mp;
    out[poff + 1] = (float)me;
    out[poff + 2] = (float)mu;
  }
}

extern "C" void kernel_launch(void* const* d_in, const int* in_sizes, int n_in,
                              void* d_out, int out_size, void* d_ws, size_t ws_size,
                              hipStream_t stream) {
  const float* z = (const float*)d_in[0];
  const int* bid = (const int*)d_in[1];
  const float* cb = (const float*)d_in[2];
  int N = in_sizes[1];
  int Dd = in_sizes[0] / N;
  int K = in_sizes[2] / Dd;
  float* out = (float*)d_out;

  // workspace layout (256B-aligned chunks)
  char* ws = (char*)d_ws;
  size_t off = 0;
  auto alloc = [&](size_t bytes) {
    void* p = ws + off;
    off += (bytes + 255) & ~(size_t)255;
    return p;
  };
  unsigned int* counts = (unsigned int*)alloc((size_t)NBATCH * K * 4);
  double* sse  = (double*)alloc(8);
  double* perp = (double*)alloc(8 * NBATCH);
  double* ent  = (double*)alloc(8 * NBATCH);
  double* uniq = (double*)alloc(8 * NBATCH);
  float* csq = (float*)alloc((size_t)K * 4);
  short* cbh = (short*)alloc((size_t)K * D64 * 2);
  unsigned int* pcnt = (unsigned int*)alloc((size_t)N * 4);
  int* cand = (int*)alloc((size_t)N * NSLOT * 4);

  size_t ioff = (size_t)N * Dd + 2;

  csq_cvt_kernel<<<(K * 64 + 255) / 256, 256, 0, stream>>>(
      cb, csq, cbh, counts, pcnt, sse, K, N);
  fused_filter_kernel<<<N / 128, 256, 0, stream>>>(z, cbh, csq, pcnt, cand, N, K);
  rescore_quant_kernel<<<N / 256, 256, 0, stream>>>(
      z, cb, csq, pcnt, cand, bid, out + ioff, out, counts, sse, N, K);
  stats_kernel<<<NBATCH, 256, 0, stream>>>(counts, perp, ent, uniq, K);
  final_kernel<<<1, 64, 0, stream>>>(sse, perp, ent, uniq, out, N);
}